// Round 1
// baseline (887.166 us; speedup 1.0000x reference)
//
#include <hip/hip_runtime.h>
#include <math.h>

// ---------------------------------------------------------------------------
// GAT IoT classifier, fp32 correctness-first pipeline.
// Layers: CSR build -> [GEMM -> attn coeffs -> softmax aggregate(+elu)] x2
//         -> fused MLP head (relu + 2-class log_softmax)
// ---------------------------------------------------------------------------

__device__ __forceinline__ float lrelu(float x) { return x > 0.f ? x : 0.2f * x; }
__device__ __forceinline__ float elu1(float x) { return x > 0.f ? x : (expf(x) - 1.f); }

// ---------------- CSR build ----------------
__global__ void zero_int_kernel(int* __restrict__ p, int n) {
  int i = blockIdx.x * blockDim.x + threadIdx.x;
  if (i < n) p[i] = 0;
}

__global__ void count_kernel(const int* __restrict__ dst, int E, int* __restrict__ indeg) {
  int e = blockIdx.x * blockDim.x + threadIdx.x;
  if (e < E) atomicAdd(&indeg[dst[e]], 1);
}

// single-block scan: off[0]=0, off[i+1]=off[i]+indeg[i]; cursor[i]=off[i]
__global__ void scan_kernel(const int* __restrict__ indeg, int* __restrict__ off,
                            int* __restrict__ cursor, int N) {
  __shared__ int temp[1024];
  __shared__ int carry_s;
  int tid = threadIdx.x;
  if (tid == 0) { carry_s = 0; off[0] = 0; }
  __syncthreads();
  for (int base = 0; base < N; base += 1024) {
    int i = base + tid;
    int v = (i < N) ? indeg[i] : 0;
    temp[tid] = v;
    __syncthreads();
    for (int o = 1; o < 1024; o <<= 1) {
      int t = (tid >= o) ? temp[tid - o] : 0;
      __syncthreads();
      temp[tid] += t;
      __syncthreads();
    }
    int incl = temp[tid];
    int carry = carry_s;
    if (i < N) {
      off[i + 1] = carry + incl;
      cursor[i] = carry + incl - v;
    }
    __syncthreads();
    if (tid == 1023) carry_s = carry + temp[1023];
    __syncthreads();
  }
}

__global__ void fill_kernel(const int* __restrict__ src, const int* __restrict__ dst, int E,
                            int* __restrict__ cursor, int* __restrict__ csr_src) {
  int e = blockIdx.x * blockDim.x + threadIdx.x;
  if (e < E) {
    int pos = atomicAdd(&cursor[dst[e]], 1);
    csr_src[pos] = src[e];
  }
}

// ---------------- fp32 tiled GEMM: C[M,N] = A[M,K] @ B[K,N] ----------------
#define BM 64
#define BN 64
#define BK 16
__launch_bounds__(256)
__global__ void sgemm_kernel(const float* __restrict__ A, const float* __restrict__ B,
                             float* __restrict__ C, int M, int N, int K) {
  __shared__ float As[BK][BM + 4];  // transposed: As[k][m]
  __shared__ float Bs[BK][BN];
  int tid = threadIdx.x;
  int bm = blockIdx.y * BM;
  int bn = blockIdx.x * BN;
  int tx = (tid & 15) * 4;  // output col offset
  int ty = (tid >> 4) * 4;  // output row offset
  int ra = tid >> 2, ca = (tid & 3) * 4;   // A-tile load coords (row, k*4)
  int rb = tid >> 4, cb = (tid & 15) * 4;  // B-tile load coords (k, col*4)
  float acc[4][4] = {};
  for (int k0 = 0; k0 < K; k0 += BK) {
    float4 av = make_float4(0.f, 0.f, 0.f, 0.f);
    if (bm + ra < M) av = *(const float4*)(A + (size_t)(bm + ra) * K + k0 + ca);
    float4 bv = *(const float4*)(B + (size_t)(k0 + rb) * N + bn + cb);
    As[ca + 0][ra] = av.x;
    As[ca + 1][ra] = av.y;
    As[ca + 2][ra] = av.z;
    As[ca + 3][ra] = av.w;
    *(float4*)&Bs[rb][cb] = bv;
    __syncthreads();
#pragma unroll
    for (int kk = 0; kk < BK; ++kk) {
      float4 a4 = *(const float4*)&As[kk][ty];
      float4 b4 = *(const float4*)&Bs[kk][tx];
      float a[4] = {a4.x, a4.y, a4.z, a4.w};
      float b[4] = {b4.x, b4.y, b4.z, b4.w};
#pragma unroll
      for (int i = 0; i < 4; ++i)
#pragma unroll
        for (int j = 0; j < 4; ++j) acc[i][j] = fmaf(a[i], b[j], acc[i][j]);
    }
    __syncthreads();
  }
#pragma unroll
  for (int i = 0; i < 4; ++i) {
    if (bm + ty + i < M) {
      float4 o = make_float4(acc[i][0], acc[i][1], acc[i][2], acc[i][3]);
      *(float4*)(C + (size_t)(bm + ty + i) * N + bn + tx) = o;
    }
  }
}

// ---------------- attention coefficients: a_s/a_d[n,h] = sum_c h[n,h,c]*att[h,c] ----
__launch_bounds__(256)
__global__ void attn_coeff_kernel(const float* __restrict__ h, const float* __restrict__ att_s,
                                  const float* __restrict__ att_d, float* __restrict__ a_s,
                                  float* __restrict__ a_d, int N) {
  int wid = (blockIdx.x * blockDim.x + threadIdx.x) >> 6;
  int lane = threadIdx.x & 63;
  if (wid >= N) return;
  float4 hv = *(const float4*)(h + (size_t)wid * 256 + lane * 4);
  float4 sv = *(const float4*)(att_s + lane * 4);
  float4 dv = *(const float4*)(att_d + lane * 4);
  float ps = hv.x * sv.x + hv.y * sv.y + hv.z * sv.z + hv.w * sv.w;
  float pd = hv.x * dv.x + hv.y * dv.y + hv.z * dv.z + hv.w * dv.w;
#pragma unroll
  for (int o = 1; o < 16; o <<= 1) {
    ps += __shfl_xor(ps, o);
    pd += __shfl_xor(pd, o);
  }
  if ((lane & 15) == 0) {
    int head = lane >> 4;
    a_s[wid * 4 + head] = ps;
    a_d[wid * 4 + head] = pd;
  }
}

// ---------------- per-node softmax aggregation (+bias, +elu) ----------------
// one wave per destination node; self-loop handled inline.
__launch_bounds__(256)
__global__ void gat_aggregate_kernel(const float* __restrict__ h, const float* __restrict__ a_s,
                                     const float* __restrict__ a_d, const int* __restrict__ off,
                                     const int* __restrict__ csr_src,
                                     const float* __restrict__ bias, float* __restrict__ outp,
                                     int N) {
  int wid = (blockIdx.x * blockDim.x + threadIdx.x) >> 6;
  int lane = threadIdx.x & 63;
  if (wid >= N) return;
  int head = lane >> 4;  // 16 lanes per head, lane handles channels [4*lane, 4*lane+4)
  float ad_n = a_d[wid * 4 + head];
  float self_logit = lrelu(a_s[wid * 4 + head] + ad_n);
  int beg = off[wid], end = off[wid + 1];
  // pass 1: per-head max (redundant across the head's 16 lanes — all identical)
  float m = self_logit;
  for (int e = beg; e < end; ++e) {
    int s = csr_src[e];
    m = fmaxf(m, lrelu(a_s[s * 4 + head] + ad_n));
  }
  // pass 2: exp-sum + weighted gather
  float z = expf(self_logit - m);
  float4 hv = *(const float4*)(h + (size_t)wid * 256 + lane * 4);
  float4 acc = make_float4(hv.x * z, hv.y * z, hv.z * z, hv.w * z);
  for (int e = beg; e < end; ++e) {
    int s = csr_src[e];
    float p = expf(lrelu(a_s[s * 4 + head] + ad_n) - m);
    z += p;
    float4 hs = *(const float4*)(h + (size_t)s * 256 + lane * 4);
    acc.x = fmaf(p, hs.x, acc.x);
    acc.y = fmaf(p, hs.y, acc.y);
    acc.z = fmaf(p, hs.z, acc.z);
    acc.w = fmaf(p, hs.w, acc.w);
  }
  float inv = 1.f / z;
  float4 bv = *(const float4*)(bias + lane * 4);
  float4 o;
  o.x = elu1(fmaf(acc.x, inv, bv.x));
  o.y = elu1(fmaf(acc.y, inv, bv.y));
  o.z = elu1(fmaf(acc.z, inv, bv.z));
  o.w = elu1(fmaf(acc.w, inv, bv.w));
  *(float4*)(outp + (size_t)wid * 256 + lane * 4) = o;
}

// ---------------- fused head: relu(h@lw1+lb1) @ lw2 + lb2 -> log_softmax ----
__launch_bounds__(256)
__global__ void mlp_head_kernel(const float* __restrict__ h, const float* __restrict__ lw1,
                                const float* __restrict__ lb1, const float* __restrict__ lw2,
                                const float* __restrict__ lb2, float* __restrict__ out, int N) {
  __shared__ float s_w[256 * 64];  // 64 KB: lw1 cached
  int tid = threadIdx.x;
  for (int i = tid; i < 256 * 64; i += 256) s_w[i] = lw1[i];
  __syncthreads();
  int lane = tid & 63;
  int wave = tid >> 6;
  float w2a = lw2[lane * 2 + 0], w2b = lw2[lane * 2 + 1];
  float bl = lb1[lane];
  float b20 = lb2[0], b21 = lb2[1];
  for (int n = blockIdx.x * 4 + wave; n < N; n += gridDim.x * 4) {
    const float* row = h + (size_t)n * 256;
    float acc = bl;
#pragma unroll 8
    for (int c = 0; c < 256; ++c) acc = fmaf(row[c], s_w[c * 64 + lane], acc);
    float r = fmaxf(acc, 0.f);
    float v0 = r * w2a, v1 = r * w2b;
#pragma unroll
    for (int o = 1; o < 64; o <<= 1) {
      v0 += __shfl_xor(v0, o);
      v1 += __shfl_xor(v1, o);
    }
    if (lane == 0) {
      v0 += b20;
      v1 += b21;
      float mx = fmaxf(v0, v1);
      float ls = mx + logf(expf(v0 - mx) + expf(v1 - mx));
      out[(size_t)n * 2 + 0] = v0 - ls;
      out[(size_t)n * 2 + 1] = v1 - ls;
    }
  }
}

// ---------------------------------------------------------------------------
static inline int cdiv(int a, int b) { return (a + b - 1) / b; }

extern "C" void kernel_launch(void* const* d_in, const int* in_sizes, int n_in,
                              void* d_out, int out_size, void* d_ws, size_t ws_size,
                              hipStream_t stream) {
  const float* x = (const float*)d_in[0];
  const int* ei = (const int*)d_in[1];
  const float* W1 = (const float*)d_in[2];
  const float* as1 = (const float*)d_in[3];
  const float* ad1 = (const float*)d_in[4];
  const float* b1 = (const float*)d_in[5];
  const float* W2 = (const float*)d_in[6];
  const float* as2 = (const float*)d_in[7];
  const float* ad2 = (const float*)d_in[8];
  const float* b2 = (const float*)d_in[9];
  const float* lw1 = (const float*)d_in[10];
  const float* lb1 = (const float*)d_in[11];
  const float* lw2 = (const float*)d_in[12];
  const float* lb2 = (const float*)d_in[13];
  float* out = (float*)d_out;

  int N = in_sizes[0] / 128;  // 50000
  int E = in_sizes[1] / 2;    // 800000

  char* ws = (char*)d_ws;
  float* hA = (float*)ws; ws += (size_t)N * 256 * sizeof(float);
  float* hB = (float*)ws; ws += (size_t)N * 256 * sizeof(float);
  float* aS = (float*)ws; ws += (size_t)N * 4 * sizeof(float);
  float* aD = (float*)ws; ws += (size_t)N * 4 * sizeof(float);
  int* indeg = (int*)ws; ws += (size_t)N * sizeof(int);
  int* cursor = (int*)ws; ws += (size_t)N * sizeof(int);
  int* off = (int*)ws; ws += (size_t)(N + 1) * sizeof(int);
  int* csr = (int*)ws; ws += (size_t)E * sizeof(int);

  const int* e_src = ei;
  const int* e_dst = ei + E;

  // CSR build
  zero_int_kernel<<<cdiv(N, 256), 256, 0, stream>>>(indeg, N);
  count_kernel<<<cdiv(E, 256), 256, 0, stream>>>(e_dst, E, indeg);
  scan_kernel<<<1, 1024, 0, stream>>>(indeg, off, cursor, N);
  fill_kernel<<<cdiv(E, 256), 256, 0, stream>>>(e_src, e_dst, E, cursor, csr);

  // Layer 1: h = x @ W1 (M=N, K=128, N=256)
  sgemm_kernel<<<dim3(256 / BN, cdiv(N, BM)), 256, 0, stream>>>(x, W1, hA, N, 256, 128);
  attn_coeff_kernel<<<cdiv(N, 4), 256, 0, stream>>>(hA, as1, ad1, aS, aD, N);
  gat_aggregate_kernel<<<cdiv(N, 4), 256, 0, stream>>>(hA, aS, aD, off, csr, b1, hB, N);

  // Layer 2: h = hB @ W2 (K=256)
  sgemm_kernel<<<dim3(256 / BN, cdiv(N, BM)), 256, 0, stream>>>(hB, W2, hA, N, 256, 256);
  attn_coeff_kernel<<<cdiv(N, 4), 256, 0, stream>>>(hA, as2, ad2, aS, aD, N);
  gat_aggregate_kernel<<<cdiv(N, 4), 256, 0, stream>>>(hA, aS, aD, off, csr, b2, hB, N);

  // Head
  mlp_head_kernel<<<512, 256, 0, stream>>>(hB, lw1, lb1, lw2, lb2, out, N);
}

// Round 2
// 695.515 us; speedup vs baseline: 1.2756x; 1.2756x over previous
//
#include <hip/hip_runtime.h>
#include <math.h>

// ---------------------------------------------------------------------------
// GAT IoT classifier — round 2.
// GEMMs: bf16 hi/lo split MFMA (3x mfma_f32_16x16x32_bf16, ~fp32 accuracy).
// Aggregate: precomputed edge logits + chunked coalesced gather w/ shfl bcast.
// Scan: 3-kernel wave-shuffle scan.
// ---------------------------------------------------------------------------

typedef __attribute__((ext_vector_type(8))) short short8v;   // 8 bf16 (4 VGPRs)
typedef __attribute__((ext_vector_type(4))) float f32x4;

__device__ __forceinline__ float lrelu(float x) { return x > 0.f ? x : 0.2f * x; }
__device__ __forceinline__ float elu1(float x) { return x > 0.f ? x : (__expf(x) - 1.f); }

__device__ __forceinline__ unsigned short bf16_rne(float v) {
  union { float f; unsigned u; } a; a.f = v;
  unsigned r = a.u + 0x7fff + ((a.u >> 16) & 1);
  return (unsigned short)(r >> 16);
}
__device__ __forceinline__ float bf16_to_f(unsigned short h) {
  union { unsigned u; float f; } a; a.u = ((unsigned)h) << 16;
  return a.f;
}

// ---------------- fp32 -> bf16 hi/lo split (elementwise) ----------------
__global__ void convert_split_kernel(const float* __restrict__ src,
                                     unsigned short* __restrict__ hi,
                                     unsigned short* __restrict__ lo, long n) {
  long i = ((long)blockIdx.x * blockDim.x + threadIdx.x) * 4;
  if (i >= n) return;
  float4 v = *(const float4*)(src + i);
  ushort4 h, l;
  h.x = bf16_rne(v.x); l.x = bf16_rne(v.x - bf16_to_f(h.x));
  h.y = bf16_rne(v.y); l.y = bf16_rne(v.y - bf16_to_f(h.y));
  h.z = bf16_rne(v.z); l.z = bf16_rne(v.z - bf16_to_f(h.z));
  h.w = bf16_rne(v.w); l.w = bf16_rne(v.w - bf16_to_f(h.w));
  *(ushort4*)(hi + i) = h;
  *(ushort4*)(lo + i) = l;
}

// ---------------- W [K][256] -> transposed bf16 hi/lo [256][K] ----------------
__global__ void convert_w_kernel(const float* __restrict__ W, unsigned short* __restrict__ thi,
                                 unsigned short* __restrict__ tlo, int K, int kshift) {
  int t = blockIdx.x * blockDim.x + threadIdx.x;
  if (t >= (K << 8)) return;
  int n = t >> kshift, k = t & (K - 1);
  float v = W[(long)k * 256 + n];
  unsigned short h = bf16_rne(v);
  thi[t] = h;
  tlo[t] = bf16_rne(v - bf16_to_f(h));
}

// ---------------- CSR build ----------------
__global__ void zero_int_kernel(int* __restrict__ p, int n) {
  int i = blockIdx.x * blockDim.x + threadIdx.x;
  if (i < n) p[i] = 0;
}

__global__ void count_kernel(const int* __restrict__ dst, int E, int* __restrict__ indeg) {
  int e = blockIdx.x * blockDim.x + threadIdx.x;
  if (e < E) atomicAdd(&indeg[dst[e]], 1);
}

// inclusive scan within 1024-blocks + block totals
__global__ void scan_block_kernel(const int* __restrict__ in, int* __restrict__ incl,
                                  int* __restrict__ bsum, int N) {
  __shared__ int wsum[16];
  int gid = blockIdx.x * 1024 + threadIdx.x;
  int lane = threadIdx.x & 63, w = threadIdx.x >> 6;
  int v = (gid < N) ? in[gid] : 0;
  int sv = v;
#pragma unroll
  for (int o = 1; o < 64; o <<= 1) {
    int t = __shfl_up(sv, o);
    if (lane >= o) sv += t;
  }
  if (lane == 63) wsum[w] = sv;
  __syncthreads();
  if (w == 0) {
    int bs = (lane < 16) ? wsum[lane] : 0;
#pragma unroll
    for (int o = 1; o < 16; o <<= 1) {
      int t = __shfl_up(bs, o);
      if (lane >= o) bs += t;
    }
    if (lane < 16) wsum[lane] = bs;
  }
  __syncthreads();
  if (w > 0) sv += wsum[w - 1];
  if (gid < N) incl[gid] = sv;
  if (threadIdx.x == 1023) bsum[blockIdx.x] = sv;
}

__global__ void scan_tops_kernel(int* __restrict__ bsum, int nb) {
  int lane = threadIdx.x;
  int v = (lane < nb) ? bsum[lane] : 0;
#pragma unroll
  for (int o = 1; o < 64; o <<= 1) {
    int t = __shfl_up(v, o);
    if (lane >= o) v += t;
  }
  if (lane < nb) bsum[lane] = v;
}

__global__ void scan_finalize_kernel(const int* __restrict__ in, const int* __restrict__ incl,
                                     const int* __restrict__ bsum, int* __restrict__ off,
                                     int* __restrict__ cursor, int N) {
  int gid = blockIdx.x * blockDim.x + threadIdx.x;
  if (gid >= N) return;
  int b = gid >> 10;
  int ic = incl[gid] + ((b > 0) ? bsum[b - 1] : 0);
  off[gid + 1] = ic;
  cursor[gid] = ic - in[gid];
  if (gid == 0) off[0] = 0;
}

__global__ void fill_kernel(const int* __restrict__ src, const int* __restrict__ dst, int E,
                            int* __restrict__ cursor, int* __restrict__ csr_src,
                            int* __restrict__ csr_dst) {
  int e = blockIdx.x * blockDim.x + threadIdx.x;
  if (e < E) {
    int d = dst[e];
    int pos = atomicAdd(&cursor[d], 1);
    csr_src[pos] = src[e];
    csr_dst[pos] = d;
  }
}

// ---------------- MFMA GEMM: C[M,256] = A[M,K] x W[K,256], bf16 hi/lo split ----
// A pre-split row-major [Mp][K]; W pre-split transposed [256][K].
__launch_bounds__(256)
__global__ void mfma_gemm_kernel(const unsigned short* __restrict__ Ahi,
                                 const unsigned short* __restrict__ Alo,
                                 const unsigned short* __restrict__ Bhi,
                                 const unsigned short* __restrict__ Blo,
                                 float* __restrict__ C, int M, int K) {
  __shared__ unsigned short As[2][64][40];  // +8 pad: stride 80B -> conflict-free b128
  __shared__ unsigned short Bs[2][64][40];
  int tid = threadIdx.x;
  int bm = blockIdx.y * 64, bn = blockIdx.x * 64;
  int lane = tid & 63, wave = tid >> 6;
  int srow = tid >> 2, sch = (tid & 3) * 8;  // staging: row, k-offset (8 bf16 = 16B)
  const unsigned short* Aph = Ahi + (long)(bm + srow) * K + sch;
  const unsigned short* Apl = Alo + (long)(bm + srow) * K + sch;
  const unsigned short* Bph = Bhi + (long)(bn + srow) * K + sch;
  const unsigned short* Bpl = Blo + (long)(bn + srow) * K + sch;
  int fm = lane & 15, fq = lane >> 4;
  f32x4 acc[4];
#pragma unroll
  for (int cb = 0; cb < 4; ++cb) acc[cb] = (f32x4){0.f, 0.f, 0.f, 0.f};
  for (int k0 = 0; k0 < K; k0 += 32) {
    uint4 va = *(const uint4*)(Aph + k0);
    uint4 vb = *(const uint4*)(Apl + k0);
    uint4 vc = *(const uint4*)(Bph + k0);
    uint4 vd = *(const uint4*)(Bpl + k0);
    *(uint4*)&As[0][srow][sch] = va;
    *(uint4*)&As[1][srow][sch] = vb;
    *(uint4*)&Bs[0][srow][sch] = vc;
    *(uint4*)&Bs[1][srow][sch] = vd;
    __syncthreads();
    short8v ah = *(const short8v*)&As[0][wave * 16 + fm][fq * 8];
    short8v al = *(const short8v*)&As[1][wave * 16 + fm][fq * 8];
#pragma unroll
    for (int cb = 0; cb < 4; ++cb) {
      short8v bh = *(const short8v*)&Bs[0][cb * 16 + fm][fq * 8];
      short8v bl = *(const short8v*)&Bs[1][cb * 16 + fm][fq * 8];
      acc[cb] = __builtin_amdgcn_mfma_f32_16x16x32_bf16(ah, bh, acc[cb], 0, 0, 0);
      acc[cb] = __builtin_amdgcn_mfma_f32_16x16x32_bf16(ah, bl, acc[cb], 0, 0, 0);
      acc[cb] = __builtin_amdgcn_mfma_f32_16x16x32_bf16(al, bh, acc[cb], 0, 0, 0);
    }
    __syncthreads();
  }
  int row0 = bm + wave * 16 + fq * 4;
#pragma unroll
  for (int cb = 0; cb < 4; ++cb) {
    int col = bn + cb * 16 + fm;
#pragma unroll
    for (int r = 0; r < 4; ++r) {
      if (row0 + r < M) C[(long)(row0 + r) * 256 + col] = acc[cb][r];
    }
  }
}

// ---------------- attention coefficients ----------------
__launch_bounds__(256)
__global__ void attn_coeff_kernel(const float* __restrict__ h, const float* __restrict__ att_s,
                                  const float* __restrict__ att_d, float* __restrict__ a_s,
                                  float* __restrict__ a_d, int N) {
  int wid = (blockIdx.x * blockDim.x + threadIdx.x) >> 6;
  int lane = threadIdx.x & 63;
  if (wid >= N) return;
  float4 hv = *(const float4*)(h + (long)wid * 256 + lane * 4);
  float4 sv = *(const float4*)(att_s + lane * 4);
  float4 dv = *(const float4*)(att_d + lane * 4);
  float ps = hv.x * sv.x + hv.y * sv.y + hv.z * sv.z + hv.w * sv.w;
  float pd = hv.x * dv.x + hv.y * dv.y + hv.z * dv.z + hv.w * dv.w;
#pragma unroll
  for (int o = 1; o < 16; o <<= 1) {
    ps += __shfl_xor(ps, o);
    pd += __shfl_xor(pd, o);
  }
  if ((lane & 15) == 0) {
    int head = lane >> 4;
    a_s[wid * 4 + head] = ps;
    a_d[wid * 4 + head] = pd;
  }
}

// ---------------- per-edge logits (CSR order, coalesced) ----------------
__global__ void edge_logits_kernel(const int* __restrict__ csr_src, const int* __restrict__ csr_dst,
                                   const float* __restrict__ a_s, const float* __restrict__ a_d,
                                   float* __restrict__ logits, int E) {
  int e = blockIdx.x * blockDim.x + threadIdx.x;
  if (e >= E) return;
  int s = csr_src[e], d = csr_dst[e];
  float4 as4 = *(const float4*)(a_s + (long)s * 4);
  float4 ad4 = *(const float4*)(a_d + (long)d * 4);
  float4 o;
  o.x = lrelu(as4.x + ad4.x);
  o.y = lrelu(as4.y + ad4.y);
  o.z = lrelu(as4.z + ad4.z);
  o.w = lrelu(as4.w + ad4.w);
  *(float4*)(logits + (long)e * 4) = o;
}

// ---------------- per-node softmax aggregation (+bias, +elu) ----------------
template <int EMIT_BF16>
__launch_bounds__(256)
__global__ void gat_aggregate2_kernel(const float* __restrict__ h, const float* __restrict__ a_s,
                                      const float* __restrict__ a_d, const int* __restrict__ off,
                                      const int* __restrict__ csr_src,
                                      const float* __restrict__ logits,
                                      const float* __restrict__ bias, float* __restrict__ out_f,
                                      unsigned short* __restrict__ out_hi,
                                      unsigned short* __restrict__ out_lo, int N) {
  int wid = (blockIdx.x * blockDim.x + threadIdx.x) >> 6;
  int lane = threadIdx.x & 63;
  if (wid >= N) return;
  int head = lane >> 4, slot = lane & 15;
  float ad_n = a_d[wid * 4 + head];
  float self_logit = lrelu(a_s[wid * 4 + head] + ad_n);
  int beg = off[wid], cnt = off[wid + 1] - beg;
  float4 hv = *(const float4*)(h + (long)wid * 256 + lane * 4);
  // pass 1: per-head max over streamed logits
  float m = self_logit;
  for (int c = slot; c < cnt; c += 16) m = fmaxf(m, logits[(long)(beg + c) * 4 + head]);
  m = fmaxf(m, __shfl_xor(m, 1));
  m = fmaxf(m, __shfl_xor(m, 2));
  m = fmaxf(m, __shfl_xor(m, 4));
  m = fmaxf(m, __shfl_xor(m, 8));
  // pass 2: chunked exp + gather
  float z = __expf(self_logit - m);
  float4 acc = make_float4(hv.x * z, hv.y * z, hv.z * z, hv.w * z);
  int base = lane & 48;
  for (int c0 = 0; c0 < cnt; c0 += 16) {
    int idx = c0 + slot;
    int sv = 0;
    float pv = 0.f;
    if (idx < cnt) {
      sv = csr_src[beg + idx];
      pv = __expf(logits[(long)(beg + idx) * 4 + head] - m);
    }
    int lim = min(16, cnt - c0);
#pragma unroll 4
    for (int j = 0; j < lim; ++j) {
      int s = __shfl(sv, j);
      float p = __shfl(pv, base | j);
      z += p;
      float4 hs = *(const float4*)(h + (long)s * 256 + lane * 4);
      acc.x = fmaf(p, hs.x, acc.x);
      acc.y = fmaf(p, hs.y, acc.y);
      acc.z = fmaf(p, hs.z, acc.z);
      acc.w = fmaf(p, hs.w, acc.w);
    }
  }
  float inv = 1.f / z;
  float4 bv = *(const float4*)(bias + lane * 4);
  float ox = elu1(fmaf(acc.x, inv, bv.x));
  float oy = elu1(fmaf(acc.y, inv, bv.y));
  float oz = elu1(fmaf(acc.z, inv, bv.z));
  float ow = elu1(fmaf(acc.w, inv, bv.w));
  if (EMIT_BF16) {
    ushort4 uh, ul;
    uh.x = bf16_rne(ox); ul.x = bf16_rne(ox - bf16_to_f(uh.x));
    uh.y = bf16_rne(oy); ul.y = bf16_rne(oy - bf16_to_f(uh.y));
    uh.z = bf16_rne(oz); ul.z = bf16_rne(oz - bf16_to_f(uh.z));
    uh.w = bf16_rne(ow); ul.w = bf16_rne(ow - bf16_to_f(uh.w));
    *(ushort4*)(out_hi + (long)wid * 256 + lane * 4) = uh;
    *(ushort4*)(out_lo + (long)wid * 256 + lane * 4) = ul;
  } else {
    *(float4*)(out_f + (long)wid * 256 + lane * 4) = make_float4(ox, oy, oz, ow);
  }
}

// ---------------- fused head: relu(h@lw1+lb1) @ lw2 + lb2 -> log_softmax ----
__launch_bounds__(256)
__global__ void mlp_head_kernel(const float* __restrict__ h, const float* __restrict__ lw1,
                                const float* __restrict__ lb1, const float* __restrict__ lw2,
                                const float* __restrict__ lb2, float* __restrict__ out, int N) {
  __shared__ float s_w[256 * 64];  // 64 KB: lw1 cached
  int tid = threadIdx.x;
  for (int i = tid; i < 256 * 64; i += 256) s_w[i] = lw1[i];
  __syncthreads();
  int lane = tid & 63;
  int wave = tid >> 6;
  float w2a = lw2[lane * 2 + 0], w2b = lw2[lane * 2 + 1];
  float bl = lb1[lane];
  float b20 = lb2[0], b21 = lb2[1];
  for (int n = blockIdx.x * 4 + wave; n < N; n += gridDim.x * 4) {
    const float* row = h + (long)n * 256;
    float acc = bl;
#pragma unroll 8
    for (int c = 0; c < 256; ++c) acc = fmaf(row[c], s_w[c * 64 + lane], acc);
    float r = fmaxf(acc, 0.f);
    float v0 = r * w2a, v1 = r * w2b;
#pragma unroll
    for (int o = 1; o < 64; o <<= 1) {
      v0 += __shfl_xor(v0, o);
      v1 += __shfl_xor(v1, o);
    }
    if (lane == 0) {
      v0 += b20;
      v1 += b21;
      float mx = fmaxf(v0, v1);
      float ls = mx + logf(expf(v0 - mx) + expf(v1 - mx));
      out[(long)n * 2 + 0] = v0 - ls;
      out[(long)n * 2 + 1] = v1 - ls;
    }
  }
}

// ---------------------------------------------------------------------------
static inline int cdiv(int a, int b) { return (a + b - 1) / b; }

extern "C" void kernel_launch(void* const* d_in, const int* in_sizes, int n_in,
                              void* d_out, int out_size, void* d_ws, size_t ws_size,
                              hipStream_t stream) {
  const float* x = (const float*)d_in[0];
  const int* ei = (const int*)d_in[1];
  const float* W1 = (const float*)d_in[2];
  const float* as1 = (const float*)d_in[3];
  const float* ad1 = (const float*)d_in[4];
  const float* b1 = (const float*)d_in[5];
  const float* W2 = (const float*)d_in[6];
  const float* as2 = (const float*)d_in[7];
  const float* ad2 = (const float*)d_in[8];
  const float* b2 = (const float*)d_in[9];
  const float* lw1 = (const float*)d_in[10];
  const float* lb1 = (const float*)d_in[11];
  const float* lw2 = (const float*)d_in[12];
  const float* lb2 = (const float*)d_in[13];
  float* out = (float*)d_out;

  int N = in_sizes[0] / 128;  // 50000
  int E = in_sizes[1] / 2;    // 800000
  int Mp = cdiv(N, 64) * 64;  // 50048 (padded rows for MFMA staging)

  char* ws = (char*)d_ws;
  unsigned short* A1hi = (unsigned short*)ws; ws += (size_t)Mp * 128 * 2;
  unsigned short* A1lo = (unsigned short*)ws; ws += (size_t)Mp * 128 * 2;
  unsigned short* Wt1hi = (unsigned short*)ws; ws += 256 * 128 * 2;
  unsigned short* Wt1lo = (unsigned short*)ws; ws += 256 * 128 * 2;
  unsigned short* Wt2hi = (unsigned short*)ws; ws += 256 * 256 * 2;
  unsigned short* Wt2lo = (unsigned short*)ws; ws += 256 * 256 * 2;
  float* hA = (float*)ws; ws += (size_t)N * 256 * 4;          // GEMM out (both layers)
  unsigned short* h2hi = (unsigned short*)ws;                  // aggregate-1 out (bf16 split)
  float* hD = (float*)ws;                                      // aggregate-2 out (aliases h2)
  ws += (size_t)Mp * 256 * 2;
  unsigned short* h2lo = (unsigned short*)ws; ws += (size_t)Mp * 256 * 2;
  float* aS = (float*)ws; ws += (size_t)N * 4 * 4;
  float* aD = (float*)ws; ws += (size_t)N * 4 * 4;
  float* logits = (float*)ws; ws += (size_t)E * 4 * 4;
  int* csr_src = (int*)ws; ws += (size_t)E * 4;
  int* csr_dst = (int*)ws; ws += (size_t)E * 4;
  int* indeg = (int*)ws; ws += (size_t)N * 4;
  int* cursor = (int*)ws; ws += (size_t)N * 4;
  int* off = (int*)ws; ws += (size_t)(N + 4) * 4;
  int* incl = (int*)ws; ws += (size_t)N * 4;
  int* bsum = (int*)ws; ws += 64 * 4;

  const int* e_src = ei;
  const int* e_dst = ei + E;
  int nb = cdiv(N, 1024);

  // input conversions
  convert_split_kernel<<<cdiv(N * 128 / 4, 256), 256, 0, stream>>>(x, A1hi, A1lo, (long)N * 128);
  convert_w_kernel<<<cdiv(256 * 128, 256), 256, 0, stream>>>(W1, Wt1hi, Wt1lo, 128, 7);
  convert_w_kernel<<<cdiv(256 * 256, 256), 256, 0, stream>>>(W2, Wt2hi, Wt2lo, 256, 8);

  // CSR build
  zero_int_kernel<<<cdiv(N, 256), 256, 0, stream>>>(indeg, N);
  count_kernel<<<cdiv(E, 256), 256, 0, stream>>>(e_dst, E, indeg);
  scan_block_kernel<<<nb, 1024, 0, stream>>>(indeg, incl, bsum, N);
  scan_tops_kernel<<<1, 64, 0, stream>>>(bsum, nb);
  scan_finalize_kernel<<<cdiv(N, 256), 256, 0, stream>>>(indeg, incl, bsum, off, cursor, N);
  fill_kernel<<<cdiv(E, 256), 256, 0, stream>>>(e_src, e_dst, E, cursor, csr_src, csr_dst);

  // Layer 1
  mfma_gemm_kernel<<<dim3(4, Mp / 64), 256, 0, stream>>>(A1hi, A1lo, Wt1hi, Wt1lo, hA, N, 128);
  attn_coeff_kernel<<<cdiv(N, 4), 256, 0, stream>>>(hA, as1, ad1, aS, aD, N);
  edge_logits_kernel<<<cdiv(E, 256), 256, 0, stream>>>(csr_src, csr_dst, aS, aD, logits, E);
  gat_aggregate2_kernel<1><<<cdiv(N, 4), 256, 0, stream>>>(hA, aS, aD, off, csr_src, logits, b1,
                                                           nullptr, h2hi, h2lo, N);

  // Layer 2
  mfma_gemm_kernel<<<dim3(4, Mp / 64), 256, 0, stream>>>(h2hi, h2lo, Wt2hi, Wt2lo, hA, N, 256);
  attn_coeff_kernel<<<cdiv(N, 4), 256, 0, stream>>>(hA, as2, ad2, aS, aD, N);
  edge_logits_kernel<<<cdiv(E, 256), 256, 0, stream>>>(csr_src, csr_dst, aS, aD, logits, E);
  gat_aggregate2_kernel<0><<<cdiv(N, 4), 256, 0, stream>>>(hA, aS, aD, off, csr_src, logits, b2,
                                                           hD, nullptr, nullptr, N);

  // Head
  mlp_head_kernel<<<512, 256, 0, stream>>>(hD, lw1, lb1, lw2, lb2, out, N);
}

// Round 3
// 565.349 us; speedup vs baseline: 1.5692x; 1.2302x over previous
//
#include <hip/hip_runtime.h>
#include <math.h>

// ---------------------------------------------------------------------------
// GAT IoT classifier — round 3.
// GEMMs: bf16 hi/lo split MFMA (3x mfma_f32_16x16x32_bf16, ~fp32 accuracy).
// Aggregate: precomputed edge logits + chunked coalesced gather w/ shfl bcast.
// Head: fused MFMA GEMM (K=256 -> 64) + lw2/log_softmax epilogue in-register.
// ---------------------------------------------------------------------------

typedef __attribute__((ext_vector_type(8))) short short8v;   // 8 bf16 (4 VGPRs)
typedef __attribute__((ext_vector_type(4))) float f32x4;

__device__ __forceinline__ float lrelu(float x) { return x > 0.f ? x : 0.2f * x; }
__device__ __forceinline__ float elu1(float x) { return x > 0.f ? x : (__expf(x) - 1.f); }

__device__ __forceinline__ unsigned short bf16_rne(float v) {
  union { float f; unsigned u; } a; a.f = v;
  unsigned r = a.u + 0x7fff + ((a.u >> 16) & 1);
  return (unsigned short)(r >> 16);
}
__device__ __forceinline__ float bf16_to_f(unsigned short h) {
  union { unsigned u; float f; } a; a.u = ((unsigned)h) << 16;
  return a.f;
}

// ---------------- fp32 -> bf16 hi/lo split (elementwise) ----------------
__global__ void convert_split_kernel(const float* __restrict__ src,
                                     unsigned short* __restrict__ hi,
                                     unsigned short* __restrict__ lo, long n) {
  long i = ((long)blockIdx.x * blockDim.x + threadIdx.x) * 4;
  if (i >= n) return;
  float4 v = *(const float4*)(src + i);
  ushort4 h, l;
  h.x = bf16_rne(v.x); l.x = bf16_rne(v.x - bf16_to_f(h.x));
  h.y = bf16_rne(v.y); l.y = bf16_rne(v.y - bf16_to_f(h.y));
  h.z = bf16_rne(v.z); l.z = bf16_rne(v.z - bf16_to_f(h.z));
  h.w = bf16_rne(v.w); l.w = bf16_rne(v.w - bf16_to_f(h.w));
  *(ushort4*)(hi + i) = h;
  *(ushort4*)(lo + i) = l;
}

// ---------------- W [K][C] -> transposed bf16 hi/lo [C][K] ----------------
__global__ void convert_w_kernel(const float* __restrict__ W, unsigned short* __restrict__ thi,
                                 unsigned short* __restrict__ tlo, int K, int kshift, int C) {
  int t = blockIdx.x * blockDim.x + threadIdx.x;
  if (t >= K * C) return;
  int n = t >> kshift, k = t & (K - 1);
  float v = W[(long)k * C + n];
  unsigned short h = bf16_rne(v);
  thi[t] = h;
  tlo[t] = bf16_rne(v - bf16_to_f(h));
}

// ---------------- CSR build ----------------
__global__ void zero_int_kernel(int* __restrict__ p, int n) {
  int i = blockIdx.x * blockDim.x + threadIdx.x;
  if (i < n) p[i] = 0;
}

__global__ void count_kernel(const int* __restrict__ dst, int E, int* __restrict__ indeg) {
  int e = blockIdx.x * blockDim.x + threadIdx.x;
  if (e < E) atomicAdd(&indeg[dst[e]], 1);
}

// inclusive scan within 1024-blocks + block totals
__global__ void scan_block_kernel(const int* __restrict__ in, int* __restrict__ incl,
                                  int* __restrict__ bsum, int N) {
  __shared__ int wsum[16];
  int gid = blockIdx.x * 1024 + threadIdx.x;
  int lane = threadIdx.x & 63, w = threadIdx.x >> 6;
  int v = (gid < N) ? in[gid] : 0;
  int sv = v;
#pragma unroll
  for (int o = 1; o < 64; o <<= 1) {
    int t = __shfl_up(sv, o);
    if (lane >= o) sv += t;
  }
  if (lane == 63) wsum[w] = sv;
  __syncthreads();
  if (w == 0) {
    int bs = (lane < 16) ? wsum[lane] : 0;
#pragma unroll
    for (int o = 1; o < 16; o <<= 1) {
      int t = __shfl_up(bs, o);
      if (lane >= o) bs += t;
    }
    if (lane < 16) wsum[lane] = bs;
  }
  __syncthreads();
  if (w > 0) sv += wsum[w - 1];
  if (gid < N) incl[gid] = sv;
  if (threadIdx.x == 1023) bsum[blockIdx.x] = sv;
}

__global__ void scan_tops_kernel(int* __restrict__ bsum, int nb) {
  int lane = threadIdx.x;
  int v = (lane < nb) ? bsum[lane] : 0;
#pragma unroll
  for (int o = 1; o < 64; o <<= 1) {
    int t = __shfl_up(v, o);
    if (lane >= o) v += t;
  }
  if (lane < nb) bsum[lane] = v;
}

__global__ void scan_finalize_kernel(const int* __restrict__ in, const int* __restrict__ incl,
                                     const int* __restrict__ bsum, int* __restrict__ off,
                                     int* __restrict__ cursor, int N) {
  int gid = blockIdx.x * blockDim.x + threadIdx.x;
  if (gid >= N) return;
  int b = gid >> 10;
  int ic = incl[gid] + ((b > 0) ? bsum[b - 1] : 0);
  off[gid + 1] = ic;
  cursor[gid] = ic - in[gid];
  if (gid == 0) off[0] = 0;
}

__global__ void fill_kernel(const int* __restrict__ src, const int* __restrict__ dst, int E,
                            int* __restrict__ cursor, int* __restrict__ csr_src,
                            int* __restrict__ csr_dst) {
  int e = blockIdx.x * blockDim.x + threadIdx.x;
  if (e < E) {
    int d = dst[e];
    int pos = atomicAdd(&cursor[d], 1);
    csr_src[pos] = src[e];
    csr_dst[pos] = d;
  }
}

// ---------------- MFMA GEMM: C[M,256] = A[M,K] x W[K,256], bf16 hi/lo split ----
// A pre-split row-major [Mp][K]; W pre-split transposed [256][K].
__launch_bounds__(256)
__global__ void mfma_gemm_kernel(const unsigned short* __restrict__ Ahi,
                                 const unsigned short* __restrict__ Alo,
                                 const unsigned short* __restrict__ Bhi,
                                 const unsigned short* __restrict__ Blo,
                                 float* __restrict__ C, int M, int K) {
  __shared__ unsigned short As[2][64][40];  // +8 pad: stride 80B -> conflict-free b128
  __shared__ unsigned short Bs[2][64][40];
  int tid = threadIdx.x;
  int bm = blockIdx.y * 64, bn = blockIdx.x * 64;
  int lane = tid & 63, wave = tid >> 6;
  int srow = tid >> 2, sch = (tid & 3) * 8;  // staging: row, k-offset (8 bf16 = 16B)
  const unsigned short* Aph = Ahi + (long)(bm + srow) * K + sch;
  const unsigned short* Apl = Alo + (long)(bm + srow) * K + sch;
  const unsigned short* Bph = Bhi + (long)(bn + srow) * K + sch;
  const unsigned short* Bpl = Blo + (long)(bn + srow) * K + sch;
  int fm = lane & 15, fq = lane >> 4;
  f32x4 acc[4];
#pragma unroll
  for (int cb = 0; cb < 4; ++cb) acc[cb] = (f32x4){0.f, 0.f, 0.f, 0.f};
  for (int k0 = 0; k0 < K; k0 += 32) {
    uint4 va = *(const uint4*)(Aph + k0);
    uint4 vb = *(const uint4*)(Apl + k0);
    uint4 vc = *(const uint4*)(Bph + k0);
    uint4 vd = *(const uint4*)(Bpl + k0);
    *(uint4*)&As[0][srow][sch] = va;
    *(uint4*)&As[1][srow][sch] = vb;
    *(uint4*)&Bs[0][srow][sch] = vc;
    *(uint4*)&Bs[1][srow][sch] = vd;
    __syncthreads();
    short8v ah = *(const short8v*)&As[0][wave * 16 + fm][fq * 8];
    short8v al = *(const short8v*)&As[1][wave * 16 + fm][fq * 8];
#pragma unroll
    for (int cb = 0; cb < 4; ++cb) {
      short8v bh = *(const short8v*)&Bs[0][cb * 16 + fm][fq * 8];
      short8v bl = *(const short8v*)&Bs[1][cb * 16 + fm][fq * 8];
      acc[cb] = __builtin_amdgcn_mfma_f32_16x16x32_bf16(ah, bh, acc[cb], 0, 0, 0);
      acc[cb] = __builtin_amdgcn_mfma_f32_16x16x32_bf16(ah, bl, acc[cb], 0, 0, 0);
      acc[cb] = __builtin_amdgcn_mfma_f32_16x16x32_bf16(al, bh, acc[cb], 0, 0, 0);
    }
    __syncthreads();
  }
  int row0 = bm + wave * 16 + fq * 4;
#pragma unroll
  for (int cb = 0; cb < 4; ++cb) {
    int col = bn + cb * 16 + fm;
#pragma unroll
    for (int r = 0; r < 4; ++r) {
      if (row0 + r < M) C[(long)(row0 + r) * 256 + col] = acc[cb][r];
    }
  }
}

// ---------------- fused MFMA head ----------------
// out = log_softmax(relu(h @ lw1 + lb1) @ lw2 + lb2); h is bf16 hi/lo split,
// lw1 pre-split transposed [64][256].
__launch_bounds__(256)
__global__ void head_mfma_kernel(const unsigned short* __restrict__ Ahi,
                                 const unsigned short* __restrict__ Alo,
                                 const unsigned short* __restrict__ Bhi,
                                 const unsigned short* __restrict__ Blo,
                                 const float* __restrict__ lb1, const float* __restrict__ lw2,
                                 const float* __restrict__ lb2, float* __restrict__ out, int M) {
  __shared__ unsigned short As[2][64][40];
  __shared__ unsigned short Bs[2][64][40];
  int tid = threadIdx.x;
  int bm = blockIdx.x * 64;
  int lane = tid & 63, wave = tid >> 6;
  int srow = tid >> 2, sch = (tid & 3) * 8;
  const unsigned short* Aph = Ahi + (long)(bm + srow) * 256 + sch;
  const unsigned short* Apl = Alo + (long)(bm + srow) * 256 + sch;
  const unsigned short* Bph = Bhi + (long)srow * 256 + sch;
  const unsigned short* Bpl = Blo + (long)srow * 256 + sch;
  int fm = lane & 15, fq = lane >> 4;
  f32x4 acc[4];
#pragma unroll
  for (int cb = 0; cb < 4; ++cb) acc[cb] = (f32x4){0.f, 0.f, 0.f, 0.f};
  for (int k0 = 0; k0 < 256; k0 += 32) {
    uint4 va = *(const uint4*)(Aph + k0);
    uint4 vb = *(const uint4*)(Apl + k0);
    uint4 vc = *(const uint4*)(Bph + k0);
    uint4 vd = *(const uint4*)(Bpl + k0);
    *(uint4*)&As[0][srow][sch] = va;
    *(uint4*)&As[1][srow][sch] = vb;
    *(uint4*)&Bs[0][srow][sch] = vc;
    *(uint4*)&Bs[1][srow][sch] = vd;
    __syncthreads();
    short8v ah = *(const short8v*)&As[0][wave * 16 + fm][fq * 8];
    short8v al = *(const short8v*)&As[1][wave * 16 + fm][fq * 8];
#pragma unroll
    for (int cb = 0; cb < 4; ++cb) {
      short8v bh = *(const short8v*)&Bs[0][cb * 16 + fm][fq * 8];
      short8v bl = *(const short8v*)&Bs[1][cb * 16 + fm][fq * 8];
      acc[cb] = __builtin_amdgcn_mfma_f32_16x16x32_bf16(ah, bh, acc[cb], 0, 0, 0);
      acc[cb] = __builtin_amdgcn_mfma_f32_16x16x32_bf16(ah, bl, acc[cb], 0, 0, 0);
      acc[cb] = __builtin_amdgcn_mfma_f32_16x16x32_bf16(al, bh, acc[cb], 0, 0, 0);
    }
    __syncthreads();
  }
  // epilogue: per-row reduce over 64 hidden cols, then 2-class log_softmax
  float lb1c[4], w20[4], w21[4];
#pragma unroll
  for (int cb = 0; cb < 4; ++cb) {
    int col = cb * 16 + fm;
    lb1c[cb] = lb1[col];
    w20[cb] = lw2[col * 2 + 0];
    w21[cb] = lw2[col * 2 + 1];
  }
  float b20 = lb2[0], b21 = lb2[1];
#pragma unroll
  for (int r = 0; r < 4; ++r) {
    float v0 = 0.f, v1 = 0.f;
#pragma unroll
    for (int cb = 0; cb < 4; ++cb) {
      float s = fmaxf(acc[cb][r] + lb1c[cb], 0.f);
      v0 = fmaf(s, w20[cb], v0);
      v1 = fmaf(s, w21[cb], v1);
    }
#pragma unroll
    for (int o = 1; o < 16; o <<= 1) {
      v0 += __shfl_xor(v0, o);
      v1 += __shfl_xor(v1, o);
    }
    if (fm == 0) {
      int row = bm + wave * 16 + fq * 4 + r;
      if (row < M) {
        v0 += b20;
        v1 += b21;
        float mx = fmaxf(v0, v1);
        float ls = mx + logf(expf(v0 - mx) + expf(v1 - mx));
        out[(long)row * 2 + 0] = v0 - ls;
        out[(long)row * 2 + 1] = v1 - ls;
      }
    }
  }
}

// ---------------- attention coefficients ----------------
__launch_bounds__(256)
__global__ void attn_coeff_kernel(const float* __restrict__ h, const float* __restrict__ att_s,
                                  const float* __restrict__ att_d, float* __restrict__ a_s,
                                  float* __restrict__ a_d, int N) {
  int wid = (blockIdx.x * blockDim.x + threadIdx.x) >> 6;
  int lane = threadIdx.x & 63;
  if (wid >= N) return;
  float4 hv = *(const float4*)(h + (long)wid * 256 + lane * 4);
  float4 sv = *(const float4*)(att_s + lane * 4);
  float4 dv = *(const float4*)(att_d + lane * 4);
  float ps = hv.x * sv.x + hv.y * sv.y + hv.z * sv.z + hv.w * sv.w;
  float pd = hv.x * dv.x + hv.y * dv.y + hv.z * dv.z + hv.w * dv.w;
#pragma unroll
  for (int o = 1; o < 16; o <<= 1) {
    ps += __shfl_xor(ps, o);
    pd += __shfl_xor(pd, o);
  }
  if ((lane & 15) == 0) {
    int head = lane >> 4;
    a_s[wid * 4 + head] = ps;
    a_d[wid * 4 + head] = pd;
  }
}

// ---------------- per-edge logits (CSR order, coalesced) ----------------
__global__ void edge_logits_kernel(const int* __restrict__ csr_src, const int* __restrict__ csr_dst,
                                   const float* __restrict__ a_s, const float* __restrict__ a_d,
                                   float* __restrict__ logits, int E) {
  int e = blockIdx.x * blockDim.x + threadIdx.x;
  if (e >= E) return;
  int s = csr_src[e], d = csr_dst[e];
  float4 as4 = *(const float4*)(a_s + (long)s * 4);
  float4 ad4 = *(const float4*)(a_d + (long)d * 4);
  float4 o;
  o.x = lrelu(as4.x + ad4.x);
  o.y = lrelu(as4.y + ad4.y);
  o.z = lrelu(as4.z + ad4.z);
  o.w = lrelu(as4.w + ad4.w);
  *(float4*)(logits + (long)e * 4) = o;
}

// ---------------- per-node softmax aggregation (+bias, +elu) ----------------
template <int EMIT_BF16>
__launch_bounds__(256)
__global__ void gat_aggregate2_kernel(const float* __restrict__ h, const float* __restrict__ a_s,
                                      const float* __restrict__ a_d, const int* __restrict__ off,
                                      const int* __restrict__ csr_src,
                                      const float* __restrict__ logits,
                                      const float* __restrict__ bias, float* __restrict__ out_f,
                                      unsigned short* __restrict__ out_hi,
                                      unsigned short* __restrict__ out_lo, int N) {
  int wid = (blockIdx.x * blockDim.x + threadIdx.x) >> 6;
  int lane = threadIdx.x & 63;
  if (wid >= N) return;
  int head = lane >> 4, slot = lane & 15;
  float ad_n = a_d[wid * 4 + head];
  float self_logit = lrelu(a_s[wid * 4 + head] + ad_n);
  int beg = off[wid], cnt = off[wid + 1] - beg;
  float4 hv = *(const float4*)(h + (long)wid * 256 + lane * 4);
  // pass 1: per-head max over streamed logits
  float m = self_logit;
  for (int c = slot; c < cnt; c += 16) m = fmaxf(m, logits[(long)(beg + c) * 4 + head]);
  m = fmaxf(m, __shfl_xor(m, 1));
  m = fmaxf(m, __shfl_xor(m, 2));
  m = fmaxf(m, __shfl_xor(m, 4));
  m = fmaxf(m, __shfl_xor(m, 8));
  // pass 2: chunked exp + gather
  float z = __expf(self_logit - m);
  float4 acc = make_float4(hv.x * z, hv.y * z, hv.z * z, hv.w * z);
  int base = lane & 48;
  for (int c0 = 0; c0 < cnt; c0 += 16) {
    int idx = c0 + slot;
    int sv = 0;
    float pv = 0.f;
    if (idx < cnt) {
      sv = csr_src[beg + idx];
      pv = __expf(logits[(long)(beg + idx) * 4 + head] - m);
    }
    int lim = min(16, cnt - c0);
#pragma unroll 4
    for (int j = 0; j < lim; ++j) {
      int s = __shfl(sv, j);
      float p = __shfl(pv, base | j);
      z += p;
      float4 hs = *(const float4*)(h + (long)s * 256 + lane * 4);
      acc.x = fmaf(p, hs.x, acc.x);
      acc.y = fmaf(p, hs.y, acc.y);
      acc.z = fmaf(p, hs.z, acc.z);
      acc.w = fmaf(p, hs.w, acc.w);
    }
  }
  float inv = 1.f / z;
  float4 bv = *(const float4*)(bias + lane * 4);
  float ox = elu1(fmaf(acc.x, inv, bv.x));
  float oy = elu1(fmaf(acc.y, inv, bv.y));
  float oz = elu1(fmaf(acc.z, inv, bv.z));
  float ow = elu1(fmaf(acc.w, inv, bv.w));
  if (EMIT_BF16) {
    ushort4 uh, ul;
    uh.x = bf16_rne(ox); ul.x = bf16_rne(ox - bf16_to_f(uh.x));
    uh.y = bf16_rne(oy); ul.y = bf16_rne(oy - bf16_to_f(uh.y));
    uh.z = bf16_rne(oz); ul.z = bf16_rne(oz - bf16_to_f(uh.z));
    uh.w = bf16_rne(ow); ul.w = bf16_rne(ow - bf16_to_f(uh.w));
    *(ushort4*)(out_hi + (long)wid * 256 + lane * 4) = uh;
    *(ushort4*)(out_lo + (long)wid * 256 + lane * 4) = ul;
  } else {
    *(float4*)(out_f + (long)wid * 256 + lane * 4) = make_float4(ox, oy, oz, ow);
  }
}

// ---------------------------------------------------------------------------
static inline int cdiv(int a, int b) { return (a + b - 1) / b; }

extern "C" void kernel_launch(void* const* d_in, const int* in_sizes, int n_in,
                              void* d_out, int out_size, void* d_ws, size_t ws_size,
                              hipStream_t stream) {
  const float* x = (const float*)d_in[0];
  const int* ei = (const int*)d_in[1];
  const float* W1 = (const float*)d_in[2];
  const float* as1 = (const float*)d_in[3];
  const float* ad1 = (const float*)d_in[4];
  const float* b1 = (const float*)d_in[5];
  const float* W2 = (const float*)d_in[6];
  const float* as2 = (const float*)d_in[7];
  const float* ad2 = (const float*)d_in[8];
  const float* b2 = (const float*)d_in[9];
  const float* lw1 = (const float*)d_in[10];
  const float* lb1 = (const float*)d_in[11];
  const float* lw2 = (const float*)d_in[12];
  const float* lb2 = (const float*)d_in[13];
  float* out = (float*)d_out;

  int N = in_sizes[0] / 128;  // 50000
  int E = in_sizes[1] / 2;    // 800000
  int Mp = cdiv(N, 64) * 64;  // 50048 (padded rows for MFMA staging)

  char* ws = (char*)d_ws;
  unsigned short* A1hi = (unsigned short*)ws; ws += (size_t)Mp * 128 * 2;
  unsigned short* A1lo = (unsigned short*)ws; ws += (size_t)Mp * 128 * 2;
  unsigned short* Wt1hi = (unsigned short*)ws; ws += 256 * 128 * 2;
  unsigned short* Wt1lo = (unsigned short*)ws; ws += 256 * 128 * 2;
  unsigned short* Wt2hi = (unsigned short*)ws; ws += 256 * 256 * 2;
  unsigned short* Wt2lo = (unsigned short*)ws; ws += 256 * 256 * 2;
  unsigned short* WLhi = (unsigned short*)ws; ws += 64 * 256 * 2;
  unsigned short* WLlo = (unsigned short*)ws; ws += 64 * 256 * 2;
  float* hA = (float*)ws; ws += (size_t)N * 256 * 4;          // GEMM out (both layers)
  unsigned short* h2hi = (unsigned short*)ws; ws += (size_t)Mp * 256 * 2;  // agg out (bf16 hi)
  unsigned short* h2lo = (unsigned short*)ws; ws += (size_t)Mp * 256 * 2;  // agg out (bf16 lo)
  float* aS = (float*)ws; ws += (size_t)N * 4 * 4;
  float* aD = (float*)ws; ws += (size_t)N * 4 * 4;
  float* logits = (float*)ws; ws += (size_t)E * 4 * 4;
  int* csr_src = (int*)ws; ws += (size_t)E * 4;
  int* csr_dst = (int*)ws; ws += (size_t)E * 4;
  int* indeg = (int*)ws; ws += (size_t)N * 4;
  int* cursor = (int*)ws; ws += (size_t)N * 4;
  int* off = (int*)ws; ws += (size_t)(N + 4) * 4;
  int* incl = (int*)ws; ws += (size_t)N * 4;
  int* bsum = (int*)ws; ws += 64 * 4;

  const int* e_src = ei;
  const int* e_dst = ei + E;
  int nb = cdiv(N, 1024);

  // input conversions
  convert_split_kernel<<<cdiv(N * 128 / 4, 256), 256, 0, stream>>>(x, A1hi, A1lo, (long)N * 128);
  convert_w_kernel<<<cdiv(256 * 128, 256), 256, 0, stream>>>(W1, Wt1hi, Wt1lo, 128, 7, 256);
  convert_w_kernel<<<cdiv(256 * 256, 256), 256, 0, stream>>>(W2, Wt2hi, Wt2lo, 256, 8, 256);
  convert_w_kernel<<<cdiv(256 * 64, 256), 256, 0, stream>>>(lw1, WLhi, WLlo, 256, 8, 64);

  // CSR build
  zero_int_kernel<<<cdiv(N, 256), 256, 0, stream>>>(indeg, N);
  count_kernel<<<cdiv(E, 256), 256, 0, stream>>>(e_dst, E, indeg);
  scan_block_kernel<<<nb, 1024, 0, stream>>>(indeg, incl, bsum, N);
  scan_tops_kernel<<<1, 64, 0, stream>>>(bsum, nb);
  scan_finalize_kernel<<<cdiv(N, 256), 256, 0, stream>>>(indeg, incl, bsum, off, cursor, N);
  fill_kernel<<<cdiv(E, 256), 256, 0, stream>>>(e_src, e_dst, E, cursor, csr_src, csr_dst);

  // Layer 1
  mfma_gemm_kernel<<<dim3(4, Mp / 64), 256, 0, stream>>>(A1hi, A1lo, Wt1hi, Wt1lo, hA, N, 128);
  attn_coeff_kernel<<<cdiv(N, 4), 256, 0, stream>>>(hA, as1, ad1, aS, aD, N);
  edge_logits_kernel<<<cdiv(E, 256), 256, 0, stream>>>(csr_src, csr_dst, aS, aD, logits, E);
  gat_aggregate2_kernel<1><<<cdiv(N, 4), 256, 0, stream>>>(hA, aS, aD, off, csr_src, logits, b1,
                                                           nullptr, h2hi, h2lo, N);

  // Layer 2
  mfma_gemm_kernel<<<dim3(4, Mp / 64), 256, 0, stream>>>(h2hi, h2lo, Wt2hi, Wt2lo, hA, N, 256);
  attn_coeff_kernel<<<cdiv(N, 4), 256, 0, stream>>>(hA, as2, ad2, aS, aD, N);
  edge_logits_kernel<<<cdiv(E, 256), 256, 0, stream>>>(csr_src, csr_dst, aS, aD, logits, E);
  gat_aggregate2_kernel<1><<<cdiv(N, 4), 256, 0, stream>>>(hA, aS, aD, off, csr_src, logits, b2,
                                                           nullptr, h2hi, h2lo, N);

  // Head (MFMA, fused epilogue)
  head_mfma_kernel<<<Mp / 64, 256, 0, stream>>>(h2hi, h2lo, WLhi, WLlo, lb1, lw2, lb2, out, N);
}

// Round 4
// 477.418 us; speedup vs baseline: 1.8583x; 1.1842x over previous
//
#include <hip/hip_runtime.h>
#include <math.h>

// ---------------------------------------------------------------------------
// GAT IoT classifier — round 4.
// GEMMs: bf16 hi/lo split MFMA (+ emit bf16-rne copy of C for the gather).
// Aggregate: bf16 gather, 8 ch/lane, TWO edges per wave-step (half-split),
//            fp32 softmax/self/bias; emits bf16 hi/lo for next GEMM/head.
// Head: fused MFMA GEMM + lw2/log_softmax epilogue.
// ---------------------------------------------------------------------------

typedef __attribute__((ext_vector_type(8))) short short8v;   // 8 bf16 (4 VGPRs)
typedef __attribute__((ext_vector_type(4))) float f32x4;

__device__ __forceinline__ float lrelu(float x) { return x > 0.f ? x : 0.2f * x; }
__device__ __forceinline__ float elu1(float x) { return x > 0.f ? x : (__expf(x) - 1.f); }

__device__ __forceinline__ unsigned short bf16_rne(float v) {
  union { float f; unsigned u; } a; a.f = v;
  unsigned r = a.u + 0x7fff + ((a.u >> 16) & 1);
  return (unsigned short)(r >> 16);
}
__device__ __forceinline__ float bf16_to_f(unsigned short h) {
  union { unsigned u; float f; } a; a.u = ((unsigned)h) << 16;
  return a.f;
}

// ---------------- fp32 -> bf16 hi/lo split (elementwise) ----------------
__global__ void convert_split_kernel(const float* __restrict__ src,
                                     unsigned short* __restrict__ hi,
                                     unsigned short* __restrict__ lo, long n) {
  long i = ((long)blockIdx.x * blockDim.x + threadIdx.x) * 4;
  if (i >= n) return;
  float4 v = *(const float4*)(src + i);
  ushort4 h, l;
  h.x = bf16_rne(v.x); l.x = bf16_rne(v.x - bf16_to_f(h.x));
  h.y = bf16_rne(v.y); l.y = bf16_rne(v.y - bf16_to_f(h.y));
  h.z = bf16_rne(v.z); l.z = bf16_rne(v.z - bf16_to_f(h.z));
  h.w = bf16_rne(v.w); l.w = bf16_rne(v.w - bf16_to_f(h.w));
  *(ushort4*)(hi + i) = h;
  *(ushort4*)(lo + i) = l;
}

// ---------------- W [K][C] -> transposed bf16 hi/lo [C][K] ----------------
__global__ void convert_w_kernel(const float* __restrict__ W, unsigned short* __restrict__ thi,
                                 unsigned short* __restrict__ tlo, int K, int kshift, int C) {
  int t = blockIdx.x * blockDim.x + threadIdx.x;
  if (t >= K * C) return;
  int n = t >> kshift, k = t & (K - 1);
  float v = W[(long)k * C + n];
  unsigned short h = bf16_rne(v);
  thi[t] = h;
  tlo[t] = bf16_rne(v - bf16_to_f(h));
}

// ---------------- CSR build ----------------
__global__ void zero_int_kernel(int* __restrict__ p, int n) {
  int i = blockIdx.x * blockDim.x + threadIdx.x;
  if (i < n) p[i] = 0;
}

__global__ void count_kernel(const int* __restrict__ dst, int E, int* __restrict__ indeg) {
  int e = blockIdx.x * blockDim.x + threadIdx.x;
  if (e < E) atomicAdd(&indeg[dst[e]], 1);
}

__global__ void scan_block_kernel(const int* __restrict__ in, int* __restrict__ incl,
                                  int* __restrict__ bsum, int N) {
  __shared__ int wsum[16];
  int gid = blockIdx.x * 1024 + threadIdx.x;
  int lane = threadIdx.x & 63, w = threadIdx.x >> 6;
  int v = (gid < N) ? in[gid] : 0;
  int sv = v;
#pragma unroll
  for (int o = 1; o < 64; o <<= 1) {
    int t = __shfl_up(sv, o);
    if (lane >= o) sv += t;
  }
  if (lane == 63) wsum[w] = sv;
  __syncthreads();
  if (w == 0) {
    int bs = (lane < 16) ? wsum[lane] : 0;
#pragma unroll
    for (int o = 1; o < 16; o <<= 1) {
      int t = __shfl_up(bs, o);
      if (lane >= o) bs += t;
    }
    if (lane < 16) wsum[lane] = bs;
  }
  __syncthreads();
  if (w > 0) sv += wsum[w - 1];
  if (gid < N) incl[gid] = sv;
  if (threadIdx.x == 1023) bsum[blockIdx.x] = sv;
}

__global__ void scan_tops_kernel(int* __restrict__ bsum, int nb) {
  int lane = threadIdx.x;
  int v = (lane < nb) ? bsum[lane] : 0;
#pragma unroll
  for (int o = 1; o < 64; o <<= 1) {
    int t = __shfl_up(v, o);
    if (lane >= o) v += t;
  }
  if (lane < nb) bsum[lane] = v;
}

__global__ void scan_finalize_kernel(const int* __restrict__ in, const int* __restrict__ incl,
                                     const int* __restrict__ bsum, int* __restrict__ off,
                                     int* __restrict__ cursor, int N) {
  int gid = blockIdx.x * blockDim.x + threadIdx.x;
  if (gid >= N) return;
  int b = gid >> 10;
  int ic = incl[gid] + ((b > 0) ? bsum[b - 1] : 0);
  off[gid + 1] = ic;
  cursor[gid] = ic - in[gid];
  if (gid == 0) off[0] = 0;
}

__global__ void fill_kernel(const int* __restrict__ src, const int* __restrict__ dst, int E,
                            int* __restrict__ cursor, int* __restrict__ csr_src,
                            int* __restrict__ csr_dst) {
  int e = blockIdx.x * blockDim.x + threadIdx.x;
  if (e < E) {
    int d = dst[e];
    int pos = atomicAdd(&cursor[d], 1);
    csr_src[pos] = src[e];
    csr_dst[pos] = d;
  }
}

// ---------------- MFMA GEMM: C[M,256] = A[M,K] x W[K,256], bf16 hi/lo split ----
// Also emits Cb = bf16_rne(C) for the downstream gather.
__launch_bounds__(256)
__global__ void mfma_gemm_kernel(const unsigned short* __restrict__ Ahi,
                                 const unsigned short* __restrict__ Alo,
                                 const unsigned short* __restrict__ Bhi,
                                 const unsigned short* __restrict__ Blo,
                                 float* __restrict__ C, unsigned short* __restrict__ Cb,
                                 int M, int K) {
  __shared__ unsigned short As[2][64][40];  // +8 pad: stride 80B -> conflict-free b128
  __shared__ unsigned short Bs[2][64][40];
  int tid = threadIdx.x;
  int bm = blockIdx.y * 64, bn = blockIdx.x * 64;
  int lane = tid & 63, wave = tid >> 6;
  int srow = tid >> 2, sch = (tid & 3) * 8;
  const unsigned short* Aph = Ahi + (long)(bm + srow) * K + sch;
  const unsigned short* Apl = Alo + (long)(bm + srow) * K + sch;
  const unsigned short* Bph = Bhi + (long)(bn + srow) * K + sch;
  const unsigned short* Bpl = Blo + (long)(bn + srow) * K + sch;
  int fm = lane & 15, fq = lane >> 4;
  f32x4 acc[4];
#pragma unroll
  for (int cb = 0; cb < 4; ++cb) acc[cb] = (f32x4){0.f, 0.f, 0.f, 0.f};
  for (int k0 = 0; k0 < K; k0 += 32) {
    uint4 va = *(const uint4*)(Aph + k0);
    uint4 vb = *(const uint4*)(Apl + k0);
    uint4 vc = *(const uint4*)(Bph + k0);
    uint4 vd = *(const uint4*)(Bpl + k0);
    *(uint4*)&As[0][srow][sch] = va;
    *(uint4*)&As[1][srow][sch] = vb;
    *(uint4*)&Bs[0][srow][sch] = vc;
    *(uint4*)&Bs[1][srow][sch] = vd;
    __syncthreads();
    short8v ah = *(const short8v*)&As[0][wave * 16 + fm][fq * 8];
    short8v al = *(const short8v*)&As[1][wave * 16 + fm][fq * 8];
#pragma unroll
    for (int cb = 0; cb < 4; ++cb) {
      short8v bh = *(const short8v*)&Bs[0][cb * 16 + fm][fq * 8];
      short8v bl = *(const short8v*)&Bs[1][cb * 16 + fm][fq * 8];
      acc[cb] = __builtin_amdgcn_mfma_f32_16x16x32_bf16(ah, bh, acc[cb], 0, 0, 0);
      acc[cb] = __builtin_amdgcn_mfma_f32_16x16x32_bf16(ah, bl, acc[cb], 0, 0, 0);
      acc[cb] = __builtin_amdgcn_mfma_f32_16x16x32_bf16(al, bh, acc[cb], 0, 0, 0);
    }
    __syncthreads();
  }
  int row0 = bm + wave * 16 + fq * 4;
#pragma unroll
  for (int cb = 0; cb < 4; ++cb) {
    int col = bn + cb * 16 + fm;
#pragma unroll
    for (int r = 0; r < 4; ++r) {
      if (row0 + r < M) {
        float v = acc[cb][r];
        C[(long)(row0 + r) * 256 + col] = v;
        Cb[(long)(row0 + r) * 256 + col] = bf16_rne(v);
      }
    }
  }
}

// ---------------- fused MFMA head ----------------
__launch_bounds__(256)
__global__ void head_mfma_kernel(const unsigned short* __restrict__ Ahi,
                                 const unsigned short* __restrict__ Alo,
                                 const unsigned short* __restrict__ Bhi,
                                 const unsigned short* __restrict__ Blo,
                                 const float* __restrict__ lb1, const float* __restrict__ lw2,
                                 const float* __restrict__ lb2, float* __restrict__ out, int M) {
  __shared__ unsigned short As[2][64][40];
  __shared__ unsigned short Bs[2][64][40];
  int tid = threadIdx.x;
  int bm = blockIdx.x * 64;
  int lane = tid & 63, wave = tid >> 6;
  int srow = tid >> 2, sch = (tid & 3) * 8;
  const unsigned short* Aph = Ahi + (long)(bm + srow) * 256 + sch;
  const unsigned short* Apl = Alo + (long)(bm + srow) * 256 + sch;
  const unsigned short* Bph = Bhi + (long)srow * 256 + sch;
  const unsigned short* Bpl = Blo + (long)srow * 256 + sch;
  int fm = lane & 15, fq = lane >> 4;
  f32x4 acc[4];
#pragma unroll
  for (int cb = 0; cb < 4; ++cb) acc[cb] = (f32x4){0.f, 0.f, 0.f, 0.f};
  for (int k0 = 0; k0 < 256; k0 += 32) {
    uint4 va = *(const uint4*)(Aph + k0);
    uint4 vb = *(const uint4*)(Apl + k0);
    uint4 vc = *(const uint4*)(Bph + k0);
    uint4 vd = *(const uint4*)(Bpl + k0);
    *(uint4*)&As[0][srow][sch] = va;
    *(uint4*)&As[1][srow][sch] = vb;
    *(uint4*)&Bs[0][srow][sch] = vc;
    *(uint4*)&Bs[1][srow][sch] = vd;
    __syncthreads();
    short8v ah = *(const short8v*)&As[0][wave * 16 + fm][fq * 8];
    short8v al = *(const short8v*)&As[1][wave * 16 + fm][fq * 8];
#pragma unroll
    for (int cb = 0; cb < 4; ++cb) {
      short8v bh = *(const short8v*)&Bs[0][cb * 16 + fm][fq * 8];
      short8v bl = *(const short8v*)&Bs[1][cb * 16 + fm][fq * 8];
      acc[cb] = __builtin_amdgcn_mfma_f32_16x16x32_bf16(ah, bh, acc[cb], 0, 0, 0);
      acc[cb] = __builtin_amdgcn_mfma_f32_16x16x32_bf16(ah, bl, acc[cb], 0, 0, 0);
      acc[cb] = __builtin_amdgcn_mfma_f32_16x16x32_bf16(al, bh, acc[cb], 0, 0, 0);
    }
    __syncthreads();
  }
  float lb1c[4], w20[4], w21[4];
#pragma unroll
  for (int cb = 0; cb < 4; ++cb) {
    int col = cb * 16 + fm;
    lb1c[cb] = lb1[col];
    w20[cb] = lw2[col * 2 + 0];
    w21[cb] = lw2[col * 2 + 1];
  }
  float b20 = lb2[0], b21 = lb2[1];
#pragma unroll
  for (int r = 0; r < 4; ++r) {
    float v0 = 0.f, v1 = 0.f;
#pragma unroll
    for (int cb = 0; cb < 4; ++cb) {
      float s = fmaxf(acc[cb][r] + lb1c[cb], 0.f);
      v0 = fmaf(s, w20[cb], v0);
      v1 = fmaf(s, w21[cb], v1);
    }
#pragma unroll
    for (int o = 1; o < 16; o <<= 1) {
      v0 += __shfl_xor(v0, o);
      v1 += __shfl_xor(v1, o);
    }
    if (fm == 0) {
      int row = bm + wave * 16 + fq * 4 + r;
      if (row < M) {
        v0 += b20;
        v1 += b21;
        float mx = fmaxf(v0, v1);
        float ls = mx + logf(expf(v0 - mx) + expf(v1 - mx));
        out[(long)row * 2 + 0] = v0 - ls;
        out[(long)row * 2 + 1] = v1 - ls;
      }
    }
  }
}

// ---------------- attention coefficients ----------------
__launch_bounds__(256)
__global__ void attn_coeff_kernel(const float* __restrict__ h, const float* __restrict__ att_s,
                                  const float* __restrict__ att_d, float* __restrict__ a_s,
                                  float* __restrict__ a_d, int N) {
  int wid = (blockIdx.x * blockDim.x + threadIdx.x) >> 6;
  int lane = threadIdx.x & 63;
  if (wid >= N) return;
  float4 hv = *(const float4*)(h + (long)wid * 256 + lane * 4);
  float4 sv = *(const float4*)(att_s + lane * 4);
  float4 dv = *(const float4*)(att_d + lane * 4);
  float ps = hv.x * sv.x + hv.y * sv.y + hv.z * sv.z + hv.w * sv.w;
  float pd = hv.x * dv.x + hv.y * dv.y + hv.z * dv.z + hv.w * dv.w;
#pragma unroll
  for (int o = 1; o < 16; o <<= 1) {
    ps += __shfl_xor(ps, o);
    pd += __shfl_xor(pd, o);
  }
  if ((lane & 15) == 0) {
    int head = lane >> 4;
    a_s[wid * 4 + head] = ps;
    a_d[wid * 4 + head] = pd;
  }
}

// ---------------- per-edge logits (CSR order, coalesced) ----------------
__global__ void edge_logits_kernel(const int* __restrict__ csr_src, const int* __restrict__ csr_dst,
                                   const float* __restrict__ a_s, const float* __restrict__ a_d,
                                   float* __restrict__ logits, int E) {
  int e = blockIdx.x * blockDim.x + threadIdx.x;
  if (e >= E) return;
  int s = csr_src[e], d = csr_dst[e];
  float4 as4 = *(const float4*)(a_s + (long)s * 4);
  float4 ad4 = *(const float4*)(a_d + (long)d * 4);
  float4 o;
  o.x = lrelu(as4.x + ad4.x);
  o.y = lrelu(as4.y + ad4.y);
  o.z = lrelu(as4.z + ad4.z);
  o.w = lrelu(as4.w + ad4.w);
  *(float4*)(logits + (long)e * 4) = o;
}

// ---------------- per-node softmax aggregation, bf16 gather, 2 edges/step ----
// lane = half*32 + c; c covers channels [8c, 8c+8); head = c>>3.
// pass-1 lane remap: lane = sl1*4 + h1 (16 slots x 4 heads, coalesced logits).
// Emits bf16 hi/lo (for next GEMM / head).
__launch_bounds__(256)
__global__ void gat_aggregate3_kernel(const unsigned short* __restrict__ hb,
                                      const float* __restrict__ hf,
                                      const float* __restrict__ a_s,
                                      const float* __restrict__ a_d,
                                      const int* __restrict__ off,
                                      const int* __restrict__ csr_src,
                                      const float* __restrict__ logits,
                                      const float* __restrict__ bias,
                                      unsigned short* __restrict__ out_hi,
                                      unsigned short* __restrict__ out_lo, int N) {
  int wid = (blockIdx.x * blockDim.x + threadIdx.x) >> 6;
  int lane = threadIdx.x & 63;
  if (wid >= N) return;
  int c = lane & 31, half = lane >> 5, head4 = c >> 3;
  int h1 = lane & 3, sl1 = lane >> 2;
  int beg = off[wid], cnt = off[wid + 1] - beg;
  // pass 1: per-head max (head = h1 for this lane)
  float self_l = lrelu(a_s[wid * 4 + h1] + a_d[wid * 4 + h1]);
  float m = self_l;
  for (int c0 = sl1; c0 < cnt; c0 += 16) m = fmaxf(m, logits[(long)(beg + c0) * 4 + h1]);
  m = fmaxf(m, __shfl_xor(m, 4));
  m = fmaxf(m, __shfl_xor(m, 8));
  m = fmaxf(m, __shfl_xor(m, 16));
  m = fmaxf(m, __shfl_xor(m, 32));
  float mh = __shfl(m, head4);       // max for my compute head
  float selfc = __shfl(self_l, head4);
  // init: half 0 carries the self contribution (fp32 row)
  float acc[8] = {};
  float z = 0.f;
  if (half == 0) {
    z = __expf(selfc - mh);
    float4 s0 = *(const float4*)(hf + (long)wid * 256 + c * 8);
    float4 s1 = *(const float4*)(hf + (long)wid * 256 + c * 8 + 4);
    acc[0] = z * s0.x; acc[1] = z * s0.y; acc[2] = z * s0.z; acc[3] = z * s0.w;
    acc[4] = z * s1.x; acc[5] = z * s1.y; acc[6] = z * s1.z; acc[7] = z * s1.w;
  }
  // pass 2: 16-edge chunks; each half gathers one edge per j-step
  for (int c0 = 0; c0 < cnt; c0 += 16) {
    int i1 = c0 + sl1;
    float pv = (i1 < cnt) ? __expf(logits[(long)(beg + i1) * 4 + h1] - m) : 0.f;
    int i2 = c0 + (lane & 15);
    int sv = (i2 < cnt) ? csr_src[beg + i2] : 0;
#pragma unroll
    for (int j = 0; j < 16; j += 2) {
      if (c0 + j >= cnt) break;
      int e = j + half;
      int s = __shfl(sv, e);
      float p = __shfl(pv, e * 4 + head4);
      z += p;
      uint4 rv = *(const uint4*)(hb + (long)s * 256 + c * 8);
      acc[0] = fmaf(p, bf16_to_f((unsigned short)(rv.x & 0xffff)), acc[0]);
      acc[1] = fmaf(p, bf16_to_f((unsigned short)(rv.x >> 16)), acc[1]);
      acc[2] = fmaf(p, bf16_to_f((unsigned short)(rv.y & 0xffff)), acc[2]);
      acc[3] = fmaf(p, bf16_to_f((unsigned short)(rv.y >> 16)), acc[3]);
      acc[4] = fmaf(p, bf16_to_f((unsigned short)(rv.z & 0xffff)), acc[4]);
      acc[5] = fmaf(p, bf16_to_f((unsigned short)(rv.z >> 16)), acc[5]);
      acc[6] = fmaf(p, bf16_to_f((unsigned short)(rv.w & 0xffff)), acc[6]);
      acc[7] = fmaf(p, bf16_to_f((unsigned short)(rv.w >> 16)), acc[7]);
    }
  }
  // combine halves
  z += __shfl_xor(z, 32);
#pragma unroll
  for (int i = 0; i < 8; ++i) acc[i] += __shfl_xor(acc[i], 32);
  if (half == 0) {
    float inv = 1.f / z;
    unsigned hi[8], lo[8];
#pragma unroll
    for (int i = 0; i < 8; ++i) {
      float o = elu1(fmaf(acc[i], inv, bias[c * 8 + i]));
      unsigned short uh = bf16_rne(o);
      hi[i] = uh;
      lo[i] = bf16_rne(o - bf16_to_f(uh));
    }
    uint4 ph, pl;
    ph.x = hi[0] | (hi[1] << 16); ph.y = hi[2] | (hi[3] << 16);
    ph.z = hi[4] | (hi[5] << 16); ph.w = hi[6] | (hi[7] << 16);
    pl.x = lo[0] | (lo[1] << 16); pl.y = lo[2] | (lo[3] << 16);
    pl.z = lo[4] | (lo[5] << 16); pl.w = lo[6] | (lo[7] << 16);
    *(uint4*)(out_hi + (long)wid * 256 + c * 8) = ph;
    *(uint4*)(out_lo + (long)wid * 256 + c * 8) = pl;
  }
}

// ---------------------------------------------------------------------------
static inline int cdiv(int a, int b) { return (a + b - 1) / b; }

extern "C" void kernel_launch(void* const* d_in, const int* in_sizes, int n_in,
                              void* d_out, int out_size, void* d_ws, size_t ws_size,
                              hipStream_t stream) {
  const float* x = (const float*)d_in[0];
  const int* ei = (const int*)d_in[1];
  const float* W1 = (const float*)d_in[2];
  const float* as1 = (const float*)d_in[3];
  const float* ad1 = (const float*)d_in[4];
  const float* b1 = (const float*)d_in[5];
  const float* W2 = (const float*)d_in[6];
  const float* as2 = (const float*)d_in[7];
  const float* ad2 = (const float*)d_in[8];
  const float* b2 = (const float*)d_in[9];
  const float* lw1 = (const float*)d_in[10];
  const float* lb1 = (const float*)d_in[11];
  const float* lw2 = (const float*)d_in[12];
  const float* lb2 = (const float*)d_in[13];
  float* out = (float*)d_out;

  int N = in_sizes[0] / 128;  // 50000
  int E = in_sizes[1] / 2;    // 800000
  int Mp = cdiv(N, 64) * 64;  // 50048

  char* ws = (char*)d_ws;
  unsigned short* A1hi = (unsigned short*)ws; ws += (size_t)Mp * 128 * 2;
  unsigned short* A1lo = (unsigned short*)ws; ws += (size_t)Mp * 128 * 2;
  unsigned short* Wt1hi = (unsigned short*)ws; ws += 256 * 128 * 2;
  unsigned short* Wt1lo = (unsigned short*)ws; ws += 256 * 128 * 2;
  unsigned short* Wt2hi = (unsigned short*)ws; ws += 256 * 256 * 2;
  unsigned short* Wt2lo = (unsigned short*)ws; ws += 256 * 256 * 2;
  unsigned short* WLhi = (unsigned short*)ws; ws += 64 * 256 * 2;
  unsigned short* WLlo = (unsigned short*)ws; ws += 64 * 256 * 2;
  float* hA = (float*)ws; ws += (size_t)Mp * 256 * 4;               // GEMM out fp32
  unsigned short* hAb = (unsigned short*)ws; ws += (size_t)Mp * 256 * 2;  // GEMM out bf16
  unsigned short* h2hi = (unsigned short*)ws; ws += (size_t)Mp * 256 * 2; // agg out hi
  unsigned short* h2lo = (unsigned short*)ws; ws += (size_t)Mp * 256 * 2; // agg out lo
  float* aS = (float*)ws; ws += (size_t)N * 4 * 4;
  float* aD = (float*)ws; ws += (size_t)N * 4 * 4;
  float* logits = (float*)ws; ws += (size_t)E * 4 * 4;
  int* csr_src = (int*)ws; ws += (size_t)E * 4;
  int* csr_dst = (int*)ws; ws += (size_t)E * 4;
  int* indeg = (int*)ws; ws += (size_t)N * 4;
  int* cursor = (int*)ws; ws += (size_t)N * 4;
  int* off = (int*)ws; ws += (size_t)(N + 4) * 4;
  int* incl = (int*)ws; ws += (size_t)N * 4;
  int* bsum = (int*)ws; ws += 64 * 4;

  const int* e_src = ei;
  const int* e_dst = ei + E;
  int nb = cdiv(N, 1024);

  // input conversions
  convert_split_kernel<<<cdiv(N * 128 / 4, 256), 256, 0, stream>>>(x, A1hi, A1lo, (long)N * 128);
  convert_w_kernel<<<cdiv(256 * 128, 256), 256, 0, stream>>>(W1, Wt1hi, Wt1lo, 128, 7, 256);
  convert_w_kernel<<<cdiv(256 * 256, 256), 256, 0, stream>>>(W2, Wt2hi, Wt2lo, 256, 8, 256);
  convert_w_kernel<<<cdiv(256 * 64, 256), 256, 0, stream>>>(lw1, WLhi, WLlo, 256, 8, 64);

  // CSR build
  zero_int_kernel<<<cdiv(N, 256), 256, 0, stream>>>(indeg, N);
  count_kernel<<<cdiv(E, 256), 256, 0, stream>>>(e_dst, E, indeg);
  scan_block_kernel<<<nb, 1024, 0, stream>>>(indeg, incl, bsum, N);
  scan_tops_kernel<<<1, 64, 0, stream>>>(bsum, nb);
  scan_finalize_kernel<<<cdiv(N, 256), 256, 0, stream>>>(indeg, incl, bsum, off, cursor, N);
  fill_kernel<<<cdiv(E, 256), 256, 0, stream>>>(e_src, e_dst, E, cursor, csr_src, csr_dst);

  // Layer 1
  mfma_gemm_kernel<<<dim3(4, Mp / 64), 256, 0, stream>>>(A1hi, A1lo, Wt1hi, Wt1lo, hA, hAb, N, 128);
  attn_coeff_kernel<<<cdiv(N, 4), 256, 0, stream>>>(hA, as1, ad1, aS, aD, N);
  edge_logits_kernel<<<cdiv(E, 256), 256, 0, stream>>>(csr_src, csr_dst, aS, aD, logits, E);
  gat_aggregate3_kernel<<<cdiv(N, 4), 256, 0, stream>>>(hAb, hA, aS, aD, off, csr_src, logits, b1,
                                                        h2hi, h2lo, N);

  // Layer 2
  mfma_gemm_kernel<<<dim3(4, Mp / 64), 256, 0, stream>>>(h2hi, h2lo, Wt2hi, Wt2lo, hA, hAb, N, 256);
  attn_coeff_kernel<<<cdiv(N, 4), 256, 0, stream>>>(hA, as2, ad2, aS, aD, N);
  edge_logits_kernel<<<cdiv(E, 256), 256, 0, stream>>>(csr_src, csr_dst, aS, aD, logits, E);
  gat_aggregate3_kernel<<<cdiv(N, 4), 256, 0, stream>>>(hAb, hA, aS, aD, off, csr_src, logits, b2,
                                                        h2hi, h2lo, N);

  // Head (MFMA, fused epilogue)
  head_mfma_kernel<<<Mp / 64, 256, 0, stream>>>(h2hi, h2lo, WLhi, WLlo, lb1, lw2, lb2, out, N);
}

// Round 5
// 450.114 us; speedup vs baseline: 1.9710x; 1.0607x over previous
//
#include <hip/hip_runtime.h>
#include <math.h>

// ---------------------------------------------------------------------------
// GAT IoT classifier — round 5.
// GEMMs: bf16 hi/lo split MFMA, emit (hi,lo) bf16 only, FUSED a_s/a_d epilogue
//        (64-col block == one head -> in-register shfl reduce, direct store).
// Aggregate: bf16 gather (hi), fp32 self row = hi+lo; emits bf16 hi/lo.
// Head: fused MFMA GEMM + lw2/log_softmax epilogue.
// ---------------------------------------------------------------------------

typedef __attribute__((ext_vector_type(8))) short short8v;   // 8 bf16 (4 VGPRs)
typedef __attribute__((ext_vector_type(4))) float f32x4;

__device__ __forceinline__ float lrelu(float x) { return x > 0.f ? x : 0.2f * x; }
__device__ __forceinline__ float elu1(float x) { return x > 0.f ? x : (__expf(x) - 1.f); }

__device__ __forceinline__ unsigned short bf16_rne(float v) {
  union { float f; unsigned u; } a; a.f = v;
  unsigned r = a.u + 0x7fff + ((a.u >> 16) & 1);
  return (unsigned short)(r >> 16);
}
__device__ __forceinline__ float bf16_to_f(unsigned short h) {
  union { unsigned u; float f; } a; a.u = ((unsigned)h) << 16;
  return a.f;
}

// ---------------- fp32 -> bf16 hi/lo split (elementwise) ----------------
__global__ void convert_split_kernel(const float* __restrict__ src,
                                     unsigned short* __restrict__ hi,
                                     unsigned short* __restrict__ lo, long n) {
  long i = ((long)blockIdx.x * blockDim.x + threadIdx.x) * 4;
  if (i >= n) return;
  float4 v = *(const float4*)(src + i);
  ushort4 h, l;
  h.x = bf16_rne(v.x); l.x = bf16_rne(v.x - bf16_to_f(h.x));
  h.y = bf16_rne(v.y); l.y = bf16_rne(v.y - bf16_to_f(h.y));
  h.z = bf16_rne(v.z); l.z = bf16_rne(v.z - bf16_to_f(h.z));
  h.w = bf16_rne(v.w); l.w = bf16_rne(v.w - bf16_to_f(h.w));
  *(ushort4*)(hi + i) = h;
  *(ushort4*)(lo + i) = l;
}

// ---------------- all weight matrices -> transposed bf16 hi/lo, one launch ----
// W1 [128][256] -> [256][128]; W2 [256][256] -> [256][256]; lw1 [256][64] -> [64][256]
__global__ void convert_weights_kernel(const float* __restrict__ W1, const float* __restrict__ W2,
                                       const float* __restrict__ lw1,
                                       unsigned short* __restrict__ o1h, unsigned short* __restrict__ o1l,
                                       unsigned short* __restrict__ o2h, unsigned short* __restrict__ o2l,
                                       unsigned short* __restrict__ o3h, unsigned short* __restrict__ o3l) {
  int t = blockIdx.x * blockDim.x + threadIdx.x;
  float v;
  unsigned short* ph;
  unsigned short* pl;
  int idx;
  if (t < 32768) {                       // W1
    int n = t >> 7, k = t & 127;
    v = W1[(long)k * 256 + n];
    ph = o1h; pl = o1l; idx = t;
  } else if (t < 98304) {                // W2
    int i = t - 32768;
    int n = i >> 8, k = i & 255;
    v = W2[(long)k * 256 + n];
    ph = o2h; pl = o2l; idx = i;
  } else if (t < 114688) {               // lw1
    int i = t - 98304;
    int n = i >> 8, k = i & 255;
    v = lw1[(long)k * 64 + n];
    ph = o3h; pl = o3l; idx = i;
  } else {
    return;
  }
  unsigned short h = bf16_rne(v);
  ph[idx] = h;
  pl[idx] = bf16_rne(v - bf16_to_f(h));
}

// ---------------- CSR build ----------------
__global__ void zero_int_kernel(int* __restrict__ p, int n) {
  int i = blockIdx.x * blockDim.x + threadIdx.x;
  if (i < n) p[i] = 0;
}

__global__ void count_kernel(const int* __restrict__ dst, int E, int* __restrict__ indeg) {
  int e = blockIdx.x * blockDim.x + threadIdx.x;
  if (e < E) atomicAdd(&indeg[dst[e]], 1);
}

__global__ void scan_block_kernel(const int* __restrict__ in, int* __restrict__ incl,
                                  int* __restrict__ bsum, int N) {
  __shared__ int wsum[16];
  int gid = blockIdx.x * 1024 + threadIdx.x;
  int lane = threadIdx.x & 63, w = threadIdx.x >> 6;
  int v = (gid < N) ? in[gid] : 0;
  int sv = v;
#pragma unroll
  for (int o = 1; o < 64; o <<= 1) {
    int t = __shfl_up(sv, o);
    if (lane >= o) sv += t;
  }
  if (lane == 63) wsum[w] = sv;
  __syncthreads();
  if (w == 0) {
    int bs = (lane < 16) ? wsum[lane] : 0;
#pragma unroll
    for (int o = 1; o < 16; o <<= 1) {
      int t = __shfl_up(bs, o);
      if (lane >= o) bs += t;
    }
    if (lane < 16) wsum[lane] = bs;
  }
  __syncthreads();
  if (w > 0) sv += wsum[w - 1];
  if (gid < N) incl[gid] = sv;
  if (threadIdx.x == 1023) bsum[blockIdx.x] = sv;
}

__global__ void scan_tops_kernel(int* __restrict__ bsum, int nb) {
  int lane = threadIdx.x;
  int v = (lane < nb) ? bsum[lane] : 0;
#pragma unroll
  for (int o = 1; o < 64; o <<= 1) {
    int t = __shfl_up(v, o);
    if (lane >= o) v += t;
  }
  if (lane < nb) bsum[lane] = v;
}

__global__ void scan_finalize_kernel(const int* __restrict__ in, const int* __restrict__ incl,
                                     const int* __restrict__ bsum, int* __restrict__ off,
                                     int* __restrict__ cursor, int N) {
  int gid = blockIdx.x * blockDim.x + threadIdx.x;
  if (gid >= N) return;
  int b = gid >> 10;
  int ic = incl[gid] + ((b > 0) ? bsum[b - 1] : 0);
  off[gid + 1] = ic;
  cursor[gid] = ic - in[gid];
  if (gid == 0) off[0] = 0;
}

__global__ void fill_kernel(const int* __restrict__ src, const int* __restrict__ dst, int E,
                            int* __restrict__ cursor, int* __restrict__ csr_src,
                            int* __restrict__ csr_dst) {
  int e = blockIdx.x * blockDim.x + threadIdx.x;
  if (e < E) {
    int d = dst[e];
    int pos = atomicAdd(&cursor[d], 1);
    csr_src[pos] = src[e];
    csr_dst[pos] = d;
  }
}

// ---------------- MFMA GEMM + fused attention-coefficient epilogue ----------
// C[M,256] = A[M,K] x W[K,256] (bf16 hi/lo split, 3 MFMAs), emits Chi/Clo bf16
// and a_s/a_d directly (bn block == one head; shfl-reduce over fm lanes).
__launch_bounds__(256)
__global__ void mfma_gemm_attn_kernel(const unsigned short* __restrict__ Ahi,
                                      const unsigned short* __restrict__ Alo,
                                      const unsigned short* __restrict__ Bhi,
                                      const unsigned short* __restrict__ Blo,
                                      const float* __restrict__ att_s,
                                      const float* __restrict__ att_d,
                                      unsigned short* __restrict__ Chi,
                                      unsigned short* __restrict__ Clo,
                                      float* __restrict__ a_s, float* __restrict__ a_d,
                                      int M, int K) {
  __shared__ unsigned short As[2][64][40];  // +8 pad: conflict-free b128
  __shared__ unsigned short Bs[2][64][40];
  int tid = threadIdx.x;
  int bm = blockIdx.y * 64, bn = blockIdx.x * 64;
  int lane = tid & 63, wave = tid >> 6;
  int srow = tid >> 2, sch = (tid & 3) * 8;
  const unsigned short* Aph = Ahi + (long)(bm + srow) * K + sch;
  const unsigned short* Apl = Alo + (long)(bm + srow) * K + sch;
  const unsigned short* Bph = Bhi + (long)(bn + srow) * K + sch;
  const unsigned short* Bpl = Blo + (long)(bn + srow) * K + sch;
  int fm = lane & 15, fq = lane >> 4;
  f32x4 acc[4];
#pragma unroll
  for (int cb = 0; cb < 4; ++cb) acc[cb] = (f32x4){0.f, 0.f, 0.f, 0.f};
  for (int k0 = 0; k0 < K; k0 += 32) {
    uint4 va = *(const uint4*)(Aph + k0);
    uint4 vb = *(const uint4*)(Apl + k0);
    uint4 vc = *(const uint4*)(Bph + k0);
    uint4 vd = *(const uint4*)(Bpl + k0);
    *(uint4*)&As[0][srow][sch] = va;
    *(uint4*)&As[1][srow][sch] = vb;
    *(uint4*)&Bs[0][srow][sch] = vc;
    *(uint4*)&Bs[1][srow][sch] = vd;
    __syncthreads();
    short8v ah = *(const short8v*)&As[0][wave * 16 + fm][fq * 8];
    short8v al = *(const short8v*)&As[1][wave * 16 + fm][fq * 8];
#pragma unroll
    for (int cb = 0; cb < 4; ++cb) {
      short8v bh = *(const short8v*)&Bs[0][cb * 16 + fm][fq * 8];
      short8v bl = *(const short8v*)&Bs[1][cb * 16 + fm][fq * 8];
      acc[cb] = __builtin_amdgcn_mfma_f32_16x16x32_bf16(ah, bh, acc[cb], 0, 0, 0);
      acc[cb] = __builtin_amdgcn_mfma_f32_16x16x32_bf16(ah, bl, acc[cb], 0, 0, 0);
      acc[cb] = __builtin_amdgcn_mfma_f32_16x16x32_bf16(al, bh, acc[cb], 0, 0, 0);
    }
    __syncthreads();
  }
  int row0 = bm + wave * 16 + fq * 4;
  int headi = bn >> 6;
  float asv[4], adv[4];
#pragma unroll
  for (int cb = 0; cb < 4; ++cb) {
    int col = bn + cb * 16 + fm;
    asv[cb] = att_s[col];
    adv[cb] = att_d[col];
  }
#pragma unroll
  for (int r = 0; r < 4; ++r) {
    int row = row0 + r;
    float sp = 0.f, dp = 0.f;
#pragma unroll
    for (int cb = 0; cb < 4; ++cb) {
      float v = acc[cb][r];
      sp = fmaf(v, asv[cb], sp);
      dp = fmaf(v, adv[cb], dp);
      if (row < M) {
        int col = bn + cb * 16 + fm;
        unsigned short hv = bf16_rne(v);
        Chi[(long)row * 256 + col] = hv;
        Clo[(long)row * 256 + col] = bf16_rne(v - bf16_to_f(hv));
      }
    }
#pragma unroll
    for (int o = 1; o < 16; o <<= 1) {
      sp += __shfl_xor(sp, o);
      dp += __shfl_xor(dp, o);
    }
    if (fm == 0 && row < M) {
      a_s[(long)row * 4 + headi] = sp;
      a_d[(long)row * 4 + headi] = dp;
    }
  }
}

// ---------------- fused MFMA head ----------------
__launch_bounds__(256)
__global__ void head_mfma_kernel(const unsigned short* __restrict__ Ahi,
                                 const unsigned short* __restrict__ Alo,
                                 const unsigned short* __restrict__ Bhi,
                                 const unsigned short* __restrict__ Blo,
                                 const float* __restrict__ lb1, const float* __restrict__ lw2,
                                 const float* __restrict__ lb2, float* __restrict__ out, int M) {
  __shared__ unsigned short As[2][64][40];
  __shared__ unsigned short Bs[2][64][40];
  int tid = threadIdx.x;
  int bm = blockIdx.x * 64;
  int lane = tid & 63, wave = tid >> 6;
  int srow = tid >> 2, sch = (tid & 3) * 8;
  const unsigned short* Aph = Ahi + (long)(bm + srow) * 256 + sch;
  const unsigned short* Apl = Alo + (long)(bm + srow) * 256 + sch;
  const unsigned short* Bph = Bhi + (long)srow * 256 + sch;
  const unsigned short* Bpl = Blo + (long)srow * 256 + sch;
  int fm = lane & 15, fq = lane >> 4;
  f32x4 acc[4];
#pragma unroll
  for (int cb = 0; cb < 4; ++cb) acc[cb] = (f32x4){0.f, 0.f, 0.f, 0.f};
  for (int k0 = 0; k0 < 256; k0 += 32) {
    uint4 va = *(const uint4*)(Aph + k0);
    uint4 vb = *(const uint4*)(Apl + k0);
    uint4 vc = *(const uint4*)(Bph + k0);
    uint4 vd = *(const uint4*)(Bpl + k0);
    *(uint4*)&As[0][srow][sch] = va;
    *(uint4*)&As[1][srow][sch] = vb;
    *(uint4*)&Bs[0][srow][sch] = vc;
    *(uint4*)&Bs[1][srow][sch] = vd;
    __syncthreads();
    short8v ah = *(const short8v*)&As[0][wave * 16 + fm][fq * 8];
    short8v al = *(const short8v*)&As[1][wave * 16 + fm][fq * 8];
#pragma unroll
    for (int cb = 0; cb < 4; ++cb) {
      short8v bh = *(const short8v*)&Bs[0][cb * 16 + fm][fq * 8];
      short8v bl = *(const short8v*)&Bs[1][cb * 16 + fm][fq * 8];
      acc[cb] = __builtin_amdgcn_mfma_f32_16x16x32_bf16(ah, bh, acc[cb], 0, 0, 0);
      acc[cb] = __builtin_amdgcn_mfma_f32_16x16x32_bf16(ah, bl, acc[cb], 0, 0, 0);
      acc[cb] = __builtin_amdgcn_mfma_f32_16x16x32_bf16(al, bh, acc[cb], 0, 0, 0);
    }
    __syncthreads();
  }
  float lb1c[4], w20[4], w21[4];
#pragma unroll
  for (int cb = 0; cb < 4; ++cb) {
    int col = cb * 16 + fm;
    lb1c[cb] = lb1[col];
    w20[cb] = lw2[col * 2 + 0];
    w21[cb] = lw2[col * 2 + 1];
  }
  float b20 = lb2[0], b21 = lb2[1];
#pragma unroll
  for (int r = 0; r < 4; ++r) {
    float v0 = 0.f, v1 = 0.f;
#pragma unroll
    for (int cb = 0; cb < 4; ++cb) {
      float s = fmaxf(acc[cb][r] + lb1c[cb], 0.f);
      v0 = fmaf(s, w20[cb], v0);
      v1 = fmaf(s, w21[cb], v1);
    }
#pragma unroll
    for (int o = 1; o < 16; o <<= 1) {
      v0 += __shfl_xor(v0, o);
      v1 += __shfl_xor(v1, o);
    }
    if (fm == 0) {
      int row = bm + wave * 16 + fq * 4 + r;
      if (row < M) {
        v0 += b20;
        v1 += b21;
        float mx = fmaxf(v0, v1);
        float ls = mx + logf(expf(v0 - mx) + expf(v1 - mx));
        out[(long)row * 2 + 0] = v0 - ls;
        out[(long)row * 2 + 1] = v1 - ls;
      }
    }
  }
}

// ---------------- per-edge logits (CSR order, coalesced) ----------------
__global__ void edge_logits_kernel(const int* __restrict__ csr_src, const int* __restrict__ csr_dst,
                                   const float* __restrict__ a_s, const float* __restrict__ a_d,
                                   float* __restrict__ logits, int E) {
  int e = blockIdx.x * blockDim.x + threadIdx.x;
  if (e >= E) return;
  int s = csr_src[e], d = csr_dst[e];
  float4 as4 = *(const float4*)(a_s + (long)s * 4);
  float4 ad4 = *(const float4*)(a_d + (long)d * 4);
  float4 o;
  o.x = lrelu(as4.x + ad4.x);
  o.y = lrelu(as4.y + ad4.y);
  o.z = lrelu(as4.z + ad4.z);
  o.w = lrelu(as4.w + ad4.w);
  *(float4*)(logits + (long)e * 4) = o;
}

// ---------------- per-node softmax aggregation, bf16 gather, 2 edges/step ----
// Self row reconstructed fp32 = hi + lo. Emits bf16 hi/lo for next GEMM/head.
__launch_bounds__(256)
__global__ void gat_aggregate3_kernel(const unsigned short* __restrict__ hhi,
                                      const unsigned short* __restrict__ hlo,
                                      const float* __restrict__ a_s,
                                      const float* __restrict__ a_d,
                                      const int* __restrict__ off,
                                      const int* __restrict__ csr_src,
                                      const float* __restrict__ logits,
                                      const float* __restrict__ bias,
                                      unsigned short* __restrict__ out_hi,
                                      unsigned short* __restrict__ out_lo, int N) {
  int wid = (blockIdx.x * blockDim.x + threadIdx.x) >> 6;
  int lane = threadIdx.x & 63;
  if (wid >= N) return;
  int c = lane & 31, half = lane >> 5, head4 = c >> 3;
  int h1 = lane & 3, sl1 = lane >> 2;
  int beg = off[wid], cnt = off[wid + 1] - beg;
  // pass 1: per-head max (head = h1 for this lane)
  float self_l = lrelu(a_s[wid * 4 + h1] + a_d[wid * 4 + h1]);
  float m = self_l;
  for (int c0 = sl1; c0 < cnt; c0 += 16) m = fmaxf(m, logits[(long)(beg + c0) * 4 + h1]);
  m = fmaxf(m, __shfl_xor(m, 4));
  m = fmaxf(m, __shfl_xor(m, 8));
  m = fmaxf(m, __shfl_xor(m, 16));
  m = fmaxf(m, __shfl_xor(m, 32));
  float mh = __shfl(m, head4);       // max for my compute head
  float selfc = __shfl(self_l, head4);
  // init: half 0 carries the self contribution (fp32 = hi+lo)
  float acc[8] = {};
  float z = 0.f;
  if (half == 0) {
    z = __expf(selfc - mh);
    uint4 rh = *(const uint4*)(hhi + (long)wid * 256 + c * 8);
    uint4 rl = *(const uint4*)(hlo + (long)wid * 256 + c * 8);
    acc[0] = z * (bf16_to_f((unsigned short)(rh.x & 0xffff)) + bf16_to_f((unsigned short)(rl.x & 0xffff)));
    acc[1] = z * (bf16_to_f((unsigned short)(rh.x >> 16)) + bf16_to_f((unsigned short)(rl.x >> 16)));
    acc[2] = z * (bf16_to_f((unsigned short)(rh.y & 0xffff)) + bf16_to_f((unsigned short)(rl.y & 0xffff)));
    acc[3] = z * (bf16_to_f((unsigned short)(rh.y >> 16)) + bf16_to_f((unsigned short)(rl.y >> 16)));
    acc[4] = z * (bf16_to_f((unsigned short)(rh.z & 0xffff)) + bf16_to_f((unsigned short)(rl.z & 0xffff)));
    acc[5] = z * (bf16_to_f((unsigned short)(rh.z >> 16)) + bf16_to_f((unsigned short)(rl.z >> 16)));
    acc[6] = z * (bf16_to_f((unsigned short)(rh.w & 0xffff)) + bf16_to_f((unsigned short)(rl.w & 0xffff)));
    acc[7] = z * (bf16_to_f((unsigned short)(rh.w >> 16)) + bf16_to_f((unsigned short)(rl.w >> 16)));
  }
  // pass 2: 16-edge chunks; each half gathers one edge per j-step
  for (int c0 = 0; c0 < cnt; c0 += 16) {
    int i1 = c0 + sl1;
    float pv = (i1 < cnt) ? __expf(logits[(long)(beg + i1) * 4 + h1] - m) : 0.f;
    int i2 = c0 + (lane & 15);
    int sv = (i2 < cnt) ? csr_src[beg + i2] : 0;
#pragma unroll
    for (int j = 0; j < 16; j += 2) {
      if (c0 + j >= cnt) break;
      int e = j + half;
      int s = __shfl(sv, e);
      float p = __shfl(pv, e * 4 + head4);
      z += p;
      uint4 rv = *(const uint4*)(hhi + (long)s * 256 + c * 8);
      acc[0] = fmaf(p, bf16_to_f((unsigned short)(rv.x & 0xffff)), acc[0]);
      acc[1] = fmaf(p, bf16_to_f((unsigned short)(rv.x >> 16)), acc[1]);
      acc[2] = fmaf(p, bf16_to_f((unsigned short)(rv.y & 0xffff)), acc[2]);
      acc[3] = fmaf(p, bf16_to_f((unsigned short)(rv.y >> 16)), acc[3]);
      acc[4] = fmaf(p, bf16_to_f((unsigned short)(rv.z & 0xffff)), acc[4]);
      acc[5] = fmaf(p, bf16_to_f((unsigned short)(rv.z >> 16)), acc[5]);
      acc[6] = fmaf(p, bf16_to_f((unsigned short)(rv.w & 0xffff)), acc[6]);
      acc[7] = fmaf(p, bf16_to_f((unsigned short)(rv.w >> 16)), acc[7]);
    }
  }
  // combine halves
  z += __shfl_xor(z, 32);
#pragma unroll
  for (int i = 0; i < 8; ++i) acc[i] += __shfl_xor(acc[i], 32);
  if (half == 0) {
    float inv = 1.f / z;
    unsigned hi[8], lo[8];
#pragma unroll
    for (int i = 0; i < 8; ++i) {
      float o = elu1(fmaf(acc[i], inv, bias[c * 8 + i]));
      unsigned short uh = bf16_rne(o);
      hi[i] = uh;
      lo[i] = bf16_rne(o - bf16_to_f(uh));
    }
    uint4 ph, pl;
    ph.x = hi[0] | (hi[1] << 16); ph.y = hi[2] | (hi[3] << 16);
    ph.z = hi[4] | (hi[5] << 16); ph.w = hi[6] | (hi[7] << 16);
    pl.x = lo[0] | (lo[1] << 16); pl.y = lo[2] | (lo[3] << 16);
    pl.z = lo[4] | (lo[5] << 16); pl.w = lo[6] | (lo[7] << 16);
    *(uint4*)(out_hi + (long)wid * 256 + c * 8) = ph;
    *(uint4*)(out_lo + (long)wid * 256 + c * 8) = pl;
  }
}

// ---------------------------------------------------------------------------
static inline int cdiv(int a, int b) { return (a + b - 1) / b; }

extern "C" void kernel_launch(void* const* d_in, const int* in_sizes, int n_in,
                              void* d_out, int out_size, void* d_ws, size_t ws_size,
                              hipStream_t stream) {
  const float* x = (const float*)d_in[0];
  const int* ei = (const int*)d_in[1];
  const float* W1 = (const float*)d_in[2];
  const float* as1 = (const float*)d_in[3];
  const float* ad1 = (const float*)d_in[4];
  const float* b1 = (const float*)d_in[5];
  const float* W2 = (const float*)d_in[6];
  const float* as2 = (const float*)d_in[7];
  const float* ad2 = (const float*)d_in[8];
  const float* b2 = (const float*)d_in[9];
  const float* lw1 = (const float*)d_in[10];
  const float* lb1 = (const float*)d_in[11];
  const float* lw2 = (const float*)d_in[12];
  const float* lb2 = (const float*)d_in[13];
  float* out = (float*)d_out;

  int N = in_sizes[0] / 128;  // 50000
  int E = in_sizes[1] / 2;    // 800000
  int Mp = cdiv(N, 64) * 64;  // 50048

  char* ws = (char*)d_ws;
  unsigned short* A1hi = (unsigned short*)ws; ws += (size_t)Mp * 128 * 2;
  unsigned short* A1lo = (unsigned short*)ws; ws += (size_t)Mp * 128 * 2;
  unsigned short* Wt1hi = (unsigned short*)ws; ws += 256 * 128 * 2;
  unsigned short* Wt1lo = (unsigned short*)ws; ws += 256 * 128 * 2;
  unsigned short* Wt2hi = (unsigned short*)ws; ws += 256 * 256 * 2;
  unsigned short* Wt2lo = (unsigned short*)ws; ws += 256 * 256 * 2;
  unsigned short* WLhi = (unsigned short*)ws; ws += 64 * 256 * 2;
  unsigned short* WLlo = (unsigned short*)ws; ws += 64 * 256 * 2;
  unsigned short* Chi = (unsigned short*)ws; ws += (size_t)Mp * 256 * 2;  // GEMM out hi
  unsigned short* Clo = (unsigned short*)ws; ws += (size_t)Mp * 256 * 2;  // GEMM out lo
  unsigned short* h2hi = (unsigned short*)ws; ws += (size_t)Mp * 256 * 2; // agg out hi
  unsigned short* h2lo = (unsigned short*)ws; ws += (size_t)Mp * 256 * 2; // agg out lo
  float* aS = (float*)ws; ws += (size_t)N * 4 * 4;
  float* aD = (float*)ws; ws += (size_t)N * 4 * 4;
  float* logits = (float*)ws; ws += (size_t)E * 4 * 4;
  int* csr_src = (int*)ws; ws += (size_t)E * 4;
  int* csr_dst = (int*)ws; ws += (size_t)E * 4;
  int* indeg = (int*)ws; ws += (size_t)N * 4;
  int* cursor = (int*)ws; ws += (size_t)N * 4;
  int* off = (int*)ws; ws += (size_t)(N + 4) * 4;
  int* incl = (int*)ws; ws += (size_t)N * 4;
  int* bsum = (int*)ws; ws += 64 * 4;

  const int* e_src = ei;
  const int* e_dst = ei + E;
  int nb = cdiv(N, 1024);

  // input conversions
  convert_split_kernel<<<cdiv(N * 128 / 4, 256), 256, 0, stream>>>(x, A1hi, A1lo, (long)N * 128);
  convert_weights_kernel<<<cdiv(114688, 256), 256, 0, stream>>>(W1, W2, lw1, Wt1hi, Wt1lo, Wt2hi,
                                                                Wt2lo, WLhi, WLlo);

  // CSR build
  zero_int_kernel<<<cdiv(N, 256), 256, 0, stream>>>(indeg, N);
  count_kernel<<<cdiv(E, 256), 256, 0, stream>>>(e_dst, E, indeg);
  scan_block_kernel<<<nb, 1024, 0, stream>>>(indeg, incl, bsum, N);
  scan_tops_kernel<<<1, 64, 0, stream>>>(bsum, nb);
  scan_finalize_kernel<<<cdiv(N, 256), 256, 0, stream>>>(indeg, incl, bsum, off, cursor, N);
  fill_kernel<<<cdiv(E, 256), 256, 0, stream>>>(e_src, e_dst, E, cursor, csr_src, csr_dst);

  // Layer 1
  mfma_gemm_attn_kernel<<<dim3(4, Mp / 64), 256, 0, stream>>>(A1hi, A1lo, Wt1hi, Wt1lo, as1, ad1,
                                                              Chi, Clo, aS, aD, N, 128);
  edge_logits_kernel<<<cdiv(E, 256), 256, 0, stream>>>(csr_src, csr_dst, aS, aD, logits, E);
  gat_aggregate3_kernel<<<cdiv(N, 4), 256, 0, stream>>>(Chi, Clo, aS, aD, off, csr_src, logits, b1,
                                                        h2hi, h2lo, N);

  // Layer 2
  mfma_gemm_attn_kernel<<<dim3(4, Mp / 64), 256, 0, stream>>>(h2hi, h2lo, Wt2hi, Wt2lo, as2, ad2,
                                                              Chi, Clo, aS, aD, N, 256);
  edge_logits_kernel<<<cdiv(E, 256), 256, 0, stream>>>(csr_src, csr_dst, aS, aD, logits, E);
  gat_aggregate3_kernel<<<cdiv(N, 4), 256, 0, stream>>>(Chi, Clo, aS, aD, off, csr_src, logits, b2,
                                                        h2hi, h2lo, N);

  // Head (MFMA, fused epilogue)
  head_mfma_kernel<<<Mp / 64, 256, 0, stream>>>(h2hi, h2lo, WLhi, WLlo, lb1, lw2, lb2, out, N);
}

// Round 7
// 389.325 us; speedup vs baseline: 2.2787x; 1.1561x over previous
//
#include <hip/hip_runtime.h>
#include <math.h>

// ---------------------------------------------------------------------------
// GAT IoT classifier — round 7 (identical to round-6 source; round-6 bench
// died on container infra, not kernel error — re-running).
// Everything fp16 single-pass: GEMMs/head = 1x mfma_f32_16x16x32_f16 (fp32
// accumulate, ~2^-11 rel err), fp16 feature tensors end-to-end.
// GEMM epilogue fuses a_s/a_d. Aggregate: fp16 gather, 2 edges/wave-step.
// ---------------------------------------------------------------------------

typedef __attribute__((ext_vector_type(8))) _Float16 half8v;  // 8 fp16 (4 VGPRs)
typedef __attribute__((ext_vector_type(4))) float f32x4;

__device__ __forceinline__ float lrelu(float x) { return x > 0.f ? x : 0.2f * x; }
__device__ __forceinline__ float elu1(float x) { return x > 0.f ? x : (__expf(x) - 1.f); }

// ---------------- fp32 -> fp16 (elementwise, 8/thread) ----------------
__global__ void convert_x_kernel(const float* __restrict__ src, _Float16* __restrict__ dst,
                                 long n) {
  long i = ((long)blockIdx.x * blockDim.x + threadIdx.x) * 8;
  if (i >= n) return;
  float4 a = *(const float4*)(src + i);
  float4 b = *(const float4*)(src + i + 4);
  half8v o = {(_Float16)a.x, (_Float16)a.y, (_Float16)a.z, (_Float16)a.w,
              (_Float16)b.x, (_Float16)b.y, (_Float16)b.z, (_Float16)b.w};
  *(half8v*)(dst + i) = o;
}

// ---------------- all weight matrices -> transposed fp16, one launch ----------
// W1 [128][256] -> [256][128]; W2 [256][256] -> [256][256]; lw1 [256][64] -> [64][256]
__global__ void convert_weights_kernel(const float* __restrict__ W1, const float* __restrict__ W2,
                                       const float* __restrict__ lw1,
                                       _Float16* __restrict__ o1, _Float16* __restrict__ o2,
                                       _Float16* __restrict__ o3) {
  int t = blockIdx.x * blockDim.x + threadIdx.x;
  if (t < 32768) {                       // W1
    int n = t >> 7, k = t & 127;
    o1[t] = (_Float16)W1[(long)k * 256 + n];
  } else if (t < 98304) {                // W2
    int i = t - 32768;
    int n = i >> 8, k = i & 255;
    o2[i] = (_Float16)W2[(long)k * 256 + n];
  } else if (t < 114688) {               // lw1
    int i = t - 98304;
    int n = i >> 8, k = i & 255;
    o3[i] = (_Float16)lw1[(long)k * 64 + n];
  }
}

// ---------------- CSR build ----------------
__global__ void zero_int_kernel(int* __restrict__ p, int n) {
  int i = blockIdx.x * blockDim.x + threadIdx.x;
  if (i < n) p[i] = 0;
}

__global__ void count_kernel(const int* __restrict__ dst, int E, int* __restrict__ indeg) {
  int e = blockIdx.x * blockDim.x + threadIdx.x;
  if (e < E) atomicAdd(&indeg[dst[e]], 1);
}

__global__ void scan_block_kernel(const int* __restrict__ in, int* __restrict__ incl,
                                  int* __restrict__ bsum, int N) {
  __shared__ int wsum[16];
  int gid = blockIdx.x * 1024 + threadIdx.x;
  int lane = threadIdx.x & 63, w = threadIdx.x >> 6;
  int v = (gid < N) ? in[gid] : 0;
  int sv = v;
#pragma unroll
  for (int o = 1; o < 64; o <<= 1) {
    int t = __shfl_up(sv, o);
    if (lane >= o) sv += t;
  }
  if (lane == 63) wsum[w] = sv;
  __syncthreads();
  if (w == 0) {
    int bs = (lane < 16) ? wsum[lane] : 0;
#pragma unroll
    for (int o = 1; o < 16; o <<= 1) {
      int t = __shfl_up(bs, o);
      if (lane >= o) bs += t;
    }
    if (lane < 16) wsum[lane] = bs;
  }
  __syncthreads();
  if (w > 0) sv += wsum[w - 1];
  if (gid < N) incl[gid] = sv;
  if (threadIdx.x == 1023) bsum[blockIdx.x] = sv;
}

__global__ void scan_tops_kernel(int* __restrict__ bsum, int nb) {
  int lane = threadIdx.x;
  int v = (lane < nb) ? bsum[lane] : 0;
#pragma unroll
  for (int o = 1; o < 64; o <<= 1) {
    int t = __shfl_up(v, o);
    if (lane >= o) v += t;
  }
  if (lane < nb) bsum[lane] = v;
}

__global__ void scan_finalize_kernel(const int* __restrict__ in, const int* __restrict__ incl,
                                     const int* __restrict__ bsum, int* __restrict__ off,
                                     int* __restrict__ cursor, int N) {
  int gid = blockIdx.x * blockDim.x + threadIdx.x;
  if (gid >= N) return;
  int b = gid >> 10;
  int ic = incl[gid] + ((b > 0) ? bsum[b - 1] : 0);
  off[gid + 1] = ic;
  cursor[gid] = ic - in[gid];
  if (gid == 0) off[0] = 0;
}

__global__ void fill_kernel(const int* __restrict__ src, const int* __restrict__ dst, int E,
                            int* __restrict__ cursor, int* __restrict__ csr_src,
                            int* __restrict__ csr_dst) {
  int e = blockIdx.x * blockDim.x + threadIdx.x;
  if (e < E) {
    int d = dst[e];
    int pos = atomicAdd(&cursor[d], 1);
    csr_src[pos] = src[e];
    csr_dst[pos] = d;
  }
}

// ---------------- fp16 MFMA GEMM + fused attention-coefficient epilogue ----
// C[M,256] = A[M,K] x W[K,256]; W transposed [256][K]; bn block == one head.
__launch_bounds__(256)
__global__ void mfma_gemm_attn_kernel(const _Float16* __restrict__ A,
                                      const _Float16* __restrict__ B,
                                      const float* __restrict__ att_s,
                                      const float* __restrict__ att_d,
                                      _Float16* __restrict__ C,
                                      float* __restrict__ a_s, float* __restrict__ a_d,
                                      int M, int K) {
  __shared__ _Float16 As[64][40];  // +8 pad: conflict-free b128
  __shared__ _Float16 Bs[64][40];
  int tid = threadIdx.x;
  int bm = blockIdx.y * 64, bn = blockIdx.x * 64;
  int lane = tid & 63, wave = tid >> 6;
  int srow = tid >> 2, sch = (tid & 3) * 8;
  const _Float16* Ap = A + (long)(bm + srow) * K + sch;
  const _Float16* Bp = B + (long)(bn + srow) * K + sch;
  int fm = lane & 15, fq = lane >> 4;
  f32x4 acc[4];
#pragma unroll
  for (int cb = 0; cb < 4; ++cb) acc[cb] = (f32x4){0.f, 0.f, 0.f, 0.f};
  for (int k0 = 0; k0 < K; k0 += 32) {
    uint4 va = *(const uint4*)(Ap + k0);
    uint4 vb = *(const uint4*)(Bp + k0);
    *(uint4*)&As[srow][sch] = va;
    *(uint4*)&Bs[srow][sch] = vb;
    __syncthreads();
    half8v ah = *(const half8v*)&As[wave * 16 + fm][fq * 8];
#pragma unroll
    for (int cb = 0; cb < 4; ++cb) {
      half8v bh = *(const half8v*)&Bs[cb * 16 + fm][fq * 8];
      acc[cb] = __builtin_amdgcn_mfma_f32_16x16x32_f16(ah, bh, acc[cb], 0, 0, 0);
    }
    __syncthreads();
  }
  int row0 = bm + wave * 16 + fq * 4;
  int headi = bn >> 6;
  float asv[4], adv[4];
#pragma unroll
  for (int cb = 0; cb < 4; ++cb) {
    int col = bn + cb * 16 + fm;
    asv[cb] = att_s[col];
    adv[cb] = att_d[col];
  }
#pragma unroll
  for (int r = 0; r < 4; ++r) {
    int row = row0 + r;
    float sp = 0.f, dp = 0.f;
#pragma unroll
    for (int cb = 0; cb < 4; ++cb) {
      float v = acc[cb][r];
      sp = fmaf(v, asv[cb], sp);
      dp = fmaf(v, adv[cb], dp);
      if (row < M) C[(long)row * 256 + bn + cb * 16 + fm] = (_Float16)v;
    }
#pragma unroll
    for (int o = 1; o < 16; o <<= 1) {
      sp += __shfl_xor(sp, o);
      dp += __shfl_xor(dp, o);
    }
    if (fm == 0 && row < M) {
      a_s[(long)row * 4 + headi] = sp;
      a_d[(long)row * 4 + headi] = dp;
    }
  }
}

// ---------------- fused fp16 MFMA head ----------------
__launch_bounds__(256)
__global__ void head_mfma_kernel(const _Float16* __restrict__ A, const _Float16* __restrict__ B,
                                 const float* __restrict__ lb1, const float* __restrict__ lw2,
                                 const float* __restrict__ lb2, float* __restrict__ out, int M) {
  __shared__ _Float16 As[64][40];
  __shared__ _Float16 Bs[64][40];
  int tid = threadIdx.x;
  int bm = blockIdx.x * 64;
  int lane = tid & 63, wave = tid >> 6;
  int srow = tid >> 2, sch = (tid & 3) * 8;
  const _Float16* Ap = A + (long)(bm + srow) * 256 + sch;
  const _Float16* Bp = B + (long)srow * 256 + sch;
  int fm = lane & 15, fq = lane >> 4;
  f32x4 acc[4];
#pragma unroll
  for (int cb = 0; cb < 4; ++cb) acc[cb] = (f32x4){0.f, 0.f, 0.f, 0.f};
  for (int k0 = 0; k0 < 256; k0 += 32) {
    uint4 va = *(const uint4*)(Ap + k0);
    uint4 vb = *(const uint4*)(Bp + k0);
    *(uint4*)&As[srow][sch] = va;
    *(uint4*)&Bs[srow][sch] = vb;
    __syncthreads();
    half8v ah = *(const half8v*)&As[wave * 16 + fm][fq * 8];
#pragma unroll
    for (int cb = 0; cb < 4; ++cb) {
      half8v bh = *(const half8v*)&Bs[cb * 16 + fm][fq * 8];
      acc[cb] = __builtin_amdgcn_mfma_f32_16x16x32_f16(ah, bh, acc[cb], 0, 0, 0);
    }
    __syncthreads();
  }
  float lb1c[4], w20[4], w21[4];
#pragma unroll
  for (int cb = 0; cb < 4; ++cb) {
    int col = cb * 16 + fm;
    lb1c[cb] = lb1[col];
    w20[cb] = lw2[col * 2 + 0];
    w21[cb] = lw2[col * 2 + 1];
  }
  float b20 = lb2[0], b21 = lb2[1];
#pragma unroll
  for (int r = 0; r < 4; ++r) {
    float v0 = 0.f, v1 = 0.f;
#pragma unroll
    for (int cb = 0; cb < 4; ++cb) {
      float s = fmaxf(acc[cb][r] + lb1c[cb], 0.f);
      v0 = fmaf(s, w20[cb], v0);
      v1 = fmaf(s, w21[cb], v1);
    }
#pragma unroll
    for (int o = 1; o < 16; o <<= 1) {
      v0 += __shfl_xor(v0, o);
      v1 += __shfl_xor(v1, o);
    }
    if (fm == 0) {
      int row = bm + wave * 16 + fq * 4 + r;
      if (row < M) {
        v0 += b20;
        v1 += b21;
        float mx = fmaxf(v0, v1);
        float ls = mx + logf(expf(v0 - mx) + expf(v1 - mx));
        out[(long)row * 2 + 0] = v0 - ls;
        out[(long)row * 2 + 1] = v1 - ls;
      }
    }
  }
}

// ---------------- per-edge logits (CSR order, coalesced) ----------------
__global__ void edge_logits_kernel(const int* __restrict__ csr_src, const int* __restrict__ csr_dst,
                                   const float* __restrict__ a_s, const float* __restrict__ a_d,
                                   float* __restrict__ logits, int E) {
  int e = blockIdx.x * blockDim.x + threadIdx.x;
  if (e >= E) return;
  int s = csr_src[e], d = csr_dst[e];
  float4 as4 = *(const float4*)(a_s + (long)s * 4);
  float4 ad4 = *(const float4*)(a_d + (long)d * 4);
  float4 o;
  o.x = lrelu(as4.x + ad4.x);
  o.y = lrelu(as4.y + ad4.y);
  o.z = lrelu(as4.z + ad4.z);
  o.w = lrelu(as4.w + ad4.w);
  *(float4*)(logits + (long)e * 4) = o;
}

// ---------------- per-node softmax aggregation, fp16 gather, 2 edges/step ----
__launch_bounds__(256)
__global__ void gat_aggregate4_kernel(const _Float16* __restrict__ h,
                                      const float* __restrict__ a_s,
                                      const float* __restrict__ a_d,
                                      const int* __restrict__ off,
                                      const int* __restrict__ csr_src,
                                      const float* __restrict__ logits,
                                      const float* __restrict__ bias,
                                      _Float16* __restrict__ outp, int N) {
  int wid = (blockIdx.x * blockDim.x + threadIdx.x) >> 6;
  int lane = threadIdx.x & 63;
  if (wid >= N) return;
  int c = lane & 31, hlf = lane >> 5, head4 = c >> 3;
  int h1 = lane & 3, sl1 = lane >> 2;
  int beg = off[wid], cnt = off[wid + 1] - beg;
  // pass 1: per-head max (head = h1 for this lane)
  float self_l = lrelu(a_s[wid * 4 + h1] + a_d[wid * 4 + h1]);
  float m = self_l;
  for (int c0 = sl1; c0 < cnt; c0 += 16) m = fmaxf(m, logits[(long)(beg + c0) * 4 + h1]);
  m = fmaxf(m, __shfl_xor(m, 4));
  m = fmaxf(m, __shfl_xor(m, 8));
  m = fmaxf(m, __shfl_xor(m, 16));
  m = fmaxf(m, __shfl_xor(m, 32));
  float mh = __shfl(m, head4);       // max for my compute head
  float selfc = __shfl(self_l, head4);
  // init: half 0 carries the self contribution
  float acc[8] = {};
  float z = 0.f;
  if (hlf == 0) {
    z = __expf(selfc - mh);
    half8v sr = *(const half8v*)(h + (long)wid * 256 + c * 8);
#pragma unroll
    for (int i = 0; i < 8; ++i) acc[i] = z * (float)sr[i];
  }
  // pass 2: 16-edge chunks; each half gathers one edge per j-step
  for (int c0 = 0; c0 < cnt; c0 += 16) {
    int i1 = c0 + sl1;
    float pv = (i1 < cnt) ? __expf(logits[(long)(beg + i1) * 4 + h1] - m) : 0.f;
    int i2 = c0 + (lane & 15);
    int sv = (i2 < cnt) ? csr_src[beg + i2] : 0;
#pragma unroll
    for (int j = 0; j < 16; j += 2) {
      if (c0 + j >= cnt) break;
      int e = j + hlf;
      int s = __shfl(sv, e);
      float p = __shfl(pv, e * 4 + head4);
      z += p;
      half8v rv = *(const half8v*)(h + (long)s * 256 + c * 8);
      acc[0] = fmaf(p, (float)rv[0], acc[0]);
      acc[1] = fmaf(p, (float)rv[1], acc[1]);
      acc[2] = fmaf(p, (float)rv[2], acc[2]);
      acc[3] = fmaf(p, (float)rv[3], acc[3]);
      acc[4] = fmaf(p, (float)rv[4], acc[4]);
      acc[5] = fmaf(p, (float)rv[5], acc[5]);
      acc[6] = fmaf(p, (float)rv[6], acc[6]);
      acc[7] = fmaf(p, (float)rv[7], acc[7]);
    }
  }
  // combine halves
  z += __shfl_xor(z, 32);
#pragma unroll
  for (int i = 0; i < 8; ++i) acc[i] += __shfl_xor(acc[i], 32);
  if (hlf == 0) {
    float inv = 1.f / z;
    half8v o;
#pragma unroll
    for (int i = 0; i < 8; ++i) o[i] = (_Float16)elu1(fmaf(acc[i], inv, bias[c * 8 + i]));
    *(half8v*)(outp + (long)wid * 256 + c * 8) = o;
  }
}

// ---------------------------------------------------------------------------
static inline int cdiv(int a, int b) { return (a + b - 1) / b; }

extern "C" void kernel_launch(void* const* d_in, const int* in_sizes, int n_in,
                              void* d_out, int out_size, void* d_ws, size_t ws_size,
                              hipStream_t stream) {
  const float* x = (const float*)d_in[0];
  const int* ei = (const int*)d_in[1];
  const float* W1 = (const float*)d_in[2];
  const float* as1 = (const float*)d_in[3];
  const float* ad1 = (const float*)d_in[4];
  const float* b1 = (const float*)d_in[5];
  const float* W2 = (const float*)d_in[6];
  const float* as2 = (const float*)d_in[7];
  const float* ad2 = (const float*)d_in[8];
  const float* b2 = (const float*)d_in[9];
  const float* lw1 = (const float*)d_in[10];
  const float* lb1 = (const float*)d_in[11];
  const float* lw2 = (const float*)d_in[12];
  const float* lb2 = (const float*)d_in[13];
  float* out = (float*)d_out;

  int N = in_sizes[0] / 128;  // 50000
  int E = in_sizes[1] / 2;    // 800000
  int Mp = cdiv(N, 64) * 64;  // 50048

  char* ws = (char*)d_ws;
  _Float16* A1 = (_Float16*)ws; ws += (size_t)Mp * 128 * 2;
  _Float16* Wt1 = (_Float16*)ws; ws += 256 * 128 * 2;
  _Float16* Wt2 = (_Float16*)ws; ws += 256 * 256 * 2;
  _Float16* WL = (_Float16*)ws; ws += 64 * 256 * 2;
  _Float16* C = (_Float16*)ws; ws += (size_t)Mp * 256 * 2;   // GEMM out
  _Float16* h2 = (_Float16*)ws; ws += (size_t)Mp * 256 * 2;  // aggregate out
  float* aS = (float*)ws; ws += (size_t)N * 4 * 4;
  float* aD = (float*)ws; ws += (size_t)N * 4 * 4;
  float* logits = (float*)ws; ws += (size_t)E * 4 * 4;
  int* csr_src = (int*)ws; ws += (size_t)E * 4;
  int* csr_dst = (int*)ws; ws += (size_t)E * 4;
  int* indeg = (int*)ws; ws += (size_t)N * 4;
  int* cursor = (int*)ws; ws += (size_t)N * 4;
  int* off = (int*)ws; ws += (size_t)(N + 4) * 4;
  int* incl = (int*)ws; ws += (size_t)N * 4;
  int* bsum = (int*)ws; ws += 64 * 4;

  const int* e_src = ei;
  const int* e_dst = ei + E;
  int nb = cdiv(N, 1024);

  // input conversions
  convert_x_kernel<<<cdiv(N * 128 / 8, 256), 256, 0, stream>>>(x, A1, (long)N * 128);
  convert_weights_kernel<<<cdiv(114688, 256), 256, 0, stream>>>(W1, W2, lw1, Wt1, Wt2, WL);

  // CSR build
  zero_int_kernel<<<cdiv(N, 256), 256, 0, stream>>>(indeg, N);
  count_kernel<<<cdiv(E, 256), 256, 0, stream>>>(e_dst, E, indeg);
  scan_block_kernel<<<nb, 1024, 0, stream>>>(indeg, incl, bsum, N);
  scan_tops_kernel<<<1, 64, 0, stream>>>(bsum, nb);
  scan_finalize_kernel<<<cdiv(N, 256), 256, 0, stream>>>(indeg, incl, bsum, off, cursor, N);
  fill_kernel<<<cdiv(E, 256), 256, 0, stream>>>(e_src, e_dst, E, cursor, csr_src, csr_dst);

  // Layer 1
  mfma_gemm_attn_kernel<<<dim3(4, Mp / 64), 256, 0, stream>>>(A1, Wt1, as1, ad1, C, aS, aD, N, 128);
  edge_logits_kernel<<<cdiv(E, 256), 256, 0, stream>>>(csr_src, csr_dst, aS, aD, logits, E);
  gat_aggregate4_kernel<<<cdiv(N, 4), 256, 0, stream>>>(C, aS, aD, off, csr_src, logits, b1, h2, N);

  // Layer 2
  mfma_gemm_attn_kernel<<<dim3(4, Mp / 64), 256, 0, stream>>>(h2, Wt2, as2, ad2, C, aS, aD, N, 256);
  edge_logits_kernel<<<cdiv(E, 256), 256, 0, stream>>>(csr_src, csr_dst, aS, aD, logits, E);
  gat_aggregate4_kernel<<<cdiv(N, 4), 256, 0, stream>>>(C, aS, aD, off, csr_src, logits, b2, h2, N);

  // Head (MFMA, fused epilogue)
  head_mfma_kernel<<<Mp / 64, 256, 0, stream>>>(h2, WL, lb1, lw2, lb2, out, N);
}

// Round 8
// 377.379 us; speedup vs baseline: 2.3509x; 1.0317x over previous
//
#include <hip/hip_runtime.h>
#include <math.h>

// ---------------------------------------------------------------------------
// GAT IoT classifier — round 8.
// fp16 single-pass MFMA GEMMs (fp32 accumulate). Fusions this round:
//  - edge_logits folded INTO the aggregate (L2-resident a_s gather, both passes)
//  - convert_x folded INTO GEMM1 staging (fp32->fp16 in-register)
//  - scan_tops folded into scan_finalize
// 11 launches total (was 15).
// ---------------------------------------------------------------------------

typedef __attribute__((ext_vector_type(8))) _Float16 half8v;  // 8 fp16 (4 VGPRs)
typedef __attribute__((ext_vector_type(4))) float f32x4;

__device__ __forceinline__ float lrelu(float x) { return x > 0.f ? x : 0.2f * x; }
__device__ __forceinline__ float elu1(float x) { return x > 0.f ? x : (__expf(x) - 1.f); }

// ---------------- all weight matrices -> transposed fp16, one launch ----------
// W1 [128][256] -> [256][128]; W2 [256][256] -> [256][256]; lw1 [256][64] -> [64][256]
__global__ void convert_weights_kernel(const float* __restrict__ W1, const float* __restrict__ W2,
                                       const float* __restrict__ lw1,
                                       _Float16* __restrict__ o1, _Float16* __restrict__ o2,
                                       _Float16* __restrict__ o3) {
  int t = blockIdx.x * blockDim.x + threadIdx.x;
  if (t < 32768) {                       // W1
    int n = t >> 7, k = t & 127;
    o1[t] = (_Float16)W1[(long)k * 256 + n];
  } else if (t < 98304) {                // W2
    int i = t - 32768;
    int n = i >> 8, k = i & 255;
    o2[i] = (_Float16)W2[(long)k * 256 + n];
  } else if (t < 114688) {               // lw1
    int i = t - 98304;
    int n = i >> 8, k = i & 255;
    o3[i] = (_Float16)lw1[(long)k * 64 + n];
  }
}

// ---------------- CSR build ----------------
__global__ void zero_int_kernel(int* __restrict__ p, int n) {
  int i = blockIdx.x * blockDim.x + threadIdx.x;
  if (i < n) p[i] = 0;
}

__global__ void count_kernel(const int* __restrict__ dst, int E, int* __restrict__ indeg) {
  int e = blockIdx.x * blockDim.x + threadIdx.x;
  if (e < E) atomicAdd(&indeg[dst[e]], 1);
}

__global__ void scan_block_kernel(const int* __restrict__ in, int* __restrict__ incl,
                                  int* __restrict__ bsum, int N) {
  __shared__ int wsum[16];
  int gid = blockIdx.x * 1024 + threadIdx.x;
  int lane = threadIdx.x & 63, w = threadIdx.x >> 6;
  int v = (gid < N) ? in[gid] : 0;
  int sv = v;
#pragma unroll
  for (int o = 1; o < 64; o <<= 1) {
    int t = __shfl_up(sv, o);
    if (lane >= o) sv += t;
  }
  if (lane == 63) wsum[w] = sv;
  __syncthreads();
  if (w == 0) {
    int bs = (lane < 16) ? wsum[lane] : 0;
#pragma unroll
    for (int o = 1; o < 16; o <<= 1) {
      int t = __shfl_up(bs, o);
      if (lane >= o) bs += t;
    }
    if (lane < 16) wsum[lane] = bs;
  }
  __syncthreads();
  if (w > 0) sv += wsum[w - 1];
  if (gid < N) incl[gid] = sv;
  if (threadIdx.x == 1023) bsum[blockIdx.x] = sv;
}

// finalize with fused block-prefix (bsum is small: <= 49 entries, L2-hot)
__global__ void scan_finalize_kernel(const int* __restrict__ in, const int* __restrict__ incl,
                                     const int* __restrict__ bsum, int* __restrict__ off,
                                     int* __restrict__ cursor, int N) {
  int gid = blockIdx.x * blockDim.x + threadIdx.x;
  if (gid >= N) return;
  int b = gid >> 10;
  int carry = 0;
  for (int k = 0; k < b; ++k) carry += bsum[k];
  int ic = incl[gid] + carry;
  off[gid + 1] = ic;
  cursor[gid] = ic - in[gid];
  if (gid == 0) off[0] = 0;
}

__global__ void fill_kernel(const int* __restrict__ src, const int* __restrict__ dst, int E,
                            int* __restrict__ cursor, int* __restrict__ csr_src) {
  int e = blockIdx.x * blockDim.x + threadIdx.x;
  if (e < E) {
    int pos = atomicAdd(&cursor[dst[e]], 1);
    csr_src[pos] = src[e];
  }
}

// ---------------- fp16 MFMA GEMM + fused attention-coefficient epilogue ----
// C[M,256] = A[M,K] x W[K,256]; W transposed [256][K]; bn block == one head.
// AT = float (layer 1: converts in staging) or _Float16.
template <typename AT>
__launch_bounds__(256)
__global__ void mfma_gemm_attn_kernel(const AT* __restrict__ A,
                                      const _Float16* __restrict__ B,
                                      const float* __restrict__ att_s,
                                      const float* __restrict__ att_d,
                                      _Float16* __restrict__ C,
                                      float* __restrict__ a_s, float* __restrict__ a_d,
                                      int M, int K) {
  __shared__ _Float16 As[64][40];  // row stride 80B (16B-multiple): b128-clean
  __shared__ _Float16 Bs[64][40];
  int tid = threadIdx.x;
  int bm = blockIdx.y * 64, bn = blockIdx.x * 64;
  int lane = tid & 63, wave = tid >> 6;
  int srow = tid >> 2, sch = (tid & 3) * 8;
  const AT* Ap = A + (long)(bm + srow) * K + sch;
  const _Float16* Bp = B + (long)(bn + srow) * K + sch;
  bool arow_ok = (bm + srow) < M;
  int fm = lane & 15, fq = lane >> 4;
  f32x4 acc[4];
#pragma unroll
  for (int cb = 0; cb < 4; ++cb) acc[cb] = (f32x4){0.f, 0.f, 0.f, 0.f};
  for (int k0 = 0; k0 < K; k0 += 32) {
    half8v a8 = {0, 0, 0, 0, 0, 0, 0, 0};
    if (arow_ok) {
      if constexpr (sizeof(AT) == 4) {
        float4 f0 = *(const float4*)(Ap + k0);
        float4 f1 = *(const float4*)(Ap + k0 + 4);
        a8 = (half8v){(_Float16)f0.x, (_Float16)f0.y, (_Float16)f0.z, (_Float16)f0.w,
                      (_Float16)f1.x, (_Float16)f1.y, (_Float16)f1.z, (_Float16)f1.w};
      } else {
        a8 = *(const half8v*)(Ap + k0);
      }
    }
    uint4 vb = *(const uint4*)(Bp + k0);
    *(half8v*)&As[srow][sch] = a8;
    *(uint4*)&Bs[srow][sch] = vb;
    __syncthreads();
    half8v ah = *(const half8v*)&As[wave * 16 + fm][fq * 8];
#pragma unroll
    for (int cb = 0; cb < 4; ++cb) {
      half8v bh = *(const half8v*)&Bs[cb * 16 + fm][fq * 8];
      acc[cb] = __builtin_amdgcn_mfma_f32_16x16x32_f16(ah, bh, acc[cb], 0, 0, 0);
    }
    __syncthreads();
  }
  int row0 = bm + wave * 16 + fq * 4;
  int headi = bn >> 6;
  float asv[4], adv[4];
#pragma unroll
  for (int cb = 0; cb < 4; ++cb) {
    int col = bn + cb * 16 + fm;
    asv[cb] = att_s[col];
    adv[cb] = att_d[col];
  }
#pragma unroll
  for (int r = 0; r < 4; ++r) {
    int row = row0 + r;
    float sp = 0.f, dp = 0.f;
#pragma unroll
    for (int cb = 0; cb < 4; ++cb) {
      float v = acc[cb][r];
      sp = fmaf(v, asv[cb], sp);
      dp = fmaf(v, adv[cb], dp);
      if (row < M) C[(long)row * 256 + bn + cb * 16 + fm] = (_Float16)v;
    }
#pragma unroll
    for (int o = 1; o < 16; o <<= 1) {
      sp += __shfl_xor(sp, o);
      dp += __shfl_xor(dp, o);
    }
    if (fm == 0 && row < M) {
      a_s[(long)row * 4 + headi] = sp;
      a_d[(long)row * 4 + headi] = dp;
    }
  }
}

// ---------------- fused fp16 MFMA head ----------------
__launch_bounds__(256)
__global__ void head_mfma_kernel(const _Float16* __restrict__ A, const _Float16* __restrict__ B,
                                 const float* __restrict__ lb1, const float* __restrict__ lw2,
                                 const float* __restrict__ lb2, float* __restrict__ out, int M) {
  __shared__ _Float16 As[64][40];
  __shared__ _Float16 Bs[64][40];
  int tid = threadIdx.x;
  int bm = blockIdx.x * 64;
  int lane = tid & 63, wave = tid >> 6;
  int srow = tid >> 2, sch = (tid & 3) * 8;
  const _Float16* Ap = A + (long)(bm + srow) * 256 + sch;
  const _Float16* Bp = B + (long)srow * 256 + sch;
  int fm = lane & 15, fq = lane >> 4;
  f32x4 acc[4];
#pragma unroll
  for (int cb = 0; cb < 4; ++cb) acc[cb] = (f32x4){0.f, 0.f, 0.f, 0.f};
  for (int k0 = 0; k0 < 256; k0 += 32) {
    uint4 va = *(const uint4*)(Ap + k0);
    uint4 vb = *(const uint4*)(Bp + k0);
    *(uint4*)&As[srow][sch] = va;
    *(uint4*)&Bs[srow][sch] = vb;
    __syncthreads();
    half8v ah = *(const half8v*)&As[wave * 16 + fm][fq * 8];
#pragma unroll
    for (int cb = 0; cb < 4; ++cb) {
      half8v bh = *(const half8v*)&Bs[cb * 16 + fm][fq * 8];
      acc[cb] = __builtin_amdgcn_mfma_f32_16x16x32_f16(ah, bh, acc[cb], 0, 0, 0);
    }
    __syncthreads();
  }
  float lb1c[4], w20[4], w21[4];
#pragma unroll
  for (int cb = 0; cb < 4; ++cb) {
    int col = cb * 16 + fm;
    lb1c[cb] = lb1[col];
    w20[cb] = lw2[col * 2 + 0];
    w21[cb] = lw2[col * 2 + 1];
  }
  float b20 = lb2[0], b21 = lb2[1];
#pragma unroll
  for (int r = 0; r < 4; ++r) {
    float v0 = 0.f, v1 = 0.f;
#pragma unroll
    for (int cb = 0; cb < 4; ++cb) {
      float s = fmaxf(acc[cb][r] + lb1c[cb], 0.f);
      v0 = fmaf(s, w20[cb], v0);
      v1 = fmaf(s, w21[cb], v1);
    }
#pragma unroll
    for (int o = 1; o < 16; o <<= 1) {
      v0 += __shfl_xor(v0, o);
      v1 += __shfl_xor(v1, o);
    }
    if (fm == 0) {
      int row = bm + wave * 16 + fq * 4 + r;
      if (row < M) {
        v0 += b20;
        v1 += b21;
        float mx = fmaxf(v0, v1);
        float ls = mx + logf(expf(v0 - mx) + expf(v1 - mx));
        out[(long)row * 2 + 0] = v0 - ls;
        out[(long)row * 2 + 1] = v1 - ls;
      }
    }
  }
}

// ---------------- per-node softmax aggregation, fused logits, fp16 gather ----
// Logits computed on the fly from a_s gathers (800 KB, L2-resident) + local a_d.
// pass-1/pv lane layout: lane = sl1*4 + h1 (16 edge slots x 4 heads).
// gather layout: lane = hlf*32 + c; c covers channels [8c, 8c+8), head4 = c>>3.
__launch_bounds__(256)
__global__ void gat_aggregate5_kernel(const _Float16* __restrict__ h,
                                      const float* __restrict__ a_s,
                                      const float* __restrict__ a_d,
                                      const int* __restrict__ off,
                                      const int* __restrict__ csr_src,
                                      const float* __restrict__ bias,
                                      _Float16* __restrict__ outp, int N) {
  int wid = (blockIdx.x * blockDim.x + threadIdx.x) >> 6;
  int lane = threadIdx.x & 63;
  if (wid >= N) return;
  int c = lane & 31, hlf = lane >> 5, head4 = c >> 3;
  int h1 = lane & 3, sl1 = lane >> 2;
  int beg = off[wid], cnt = off[wid + 1] - beg;
  float ad_h1 = a_d[wid * 4 + h1];
  float self_l = lrelu(a_s[wid * 4 + h1] + ad_h1);
  // pass 1: per-head max, logits computed in-flight
  float m = self_l;
  for (int c0 = sl1; c0 < cnt; c0 += 16) {
    int s = csr_src[beg + c0];
    m = fmaxf(m, lrelu(a_s[(long)s * 4 + h1] + ad_h1));
  }
  m = fmaxf(m, __shfl_xor(m, 4));
  m = fmaxf(m, __shfl_xor(m, 8));
  m = fmaxf(m, __shfl_xor(m, 16));
  m = fmaxf(m, __shfl_xor(m, 32));
  float mh = __shfl(m, head4);       // max for my compute head
  float selfc = __shfl(self_l, head4);
  // init: half 0 carries the self contribution
  float acc[8] = {};
  float z = 0.f;
  if (hlf == 0) {
    z = __expf(selfc - mh);
    half8v sr = *(const half8v*)(h + (long)wid * 256 + c * 8);
#pragma unroll
    for (int i = 0; i < 8; ++i) acc[i] = z * (float)sr[i];
  }
  // pass 2: 16-edge chunks; each half gathers one edge per j-step
  for (int c0 = 0; c0 < cnt; c0 += 16) {
    int i2 = c0 + (lane & 15);
    int sv = (i2 < cnt) ? csr_src[beg + i2] : 0;
    int i1 = c0 + sl1;
    int sp = __shfl(sv, sl1);  // src of edge i1 (lane sl1 holds it)
    float pv = 0.f;
    if (i1 < cnt) pv = __expf(lrelu(a_s[(long)sp * 4 + h1] + ad_h1) - m);
#pragma unroll
    for (int j = 0; j < 16; j += 2) {
      if (c0 + j >= cnt) break;
      int e = j + hlf;
      int s = __shfl(sv, e);
      float p = __shfl(pv, e * 4 + head4);
      z += p;
      half8v rv = *(const half8v*)(h + (long)s * 256 + c * 8);
      acc[0] = fmaf(p, (float)rv[0], acc[0]);
      acc[1] = fmaf(p, (float)rv[1], acc[1]);
      acc[2] = fmaf(p, (float)rv[2], acc[2]);
      acc[3] = fmaf(p, (float)rv[3], acc[3]);
      acc[4] = fmaf(p, (float)rv[4], acc[4]);
      acc[5] = fmaf(p, (float)rv[5], acc[5]);
      acc[6] = fmaf(p, (float)rv[6], acc[6]);
      acc[7] = fmaf(p, (float)rv[7], acc[7]);
    }
  }
  // combine halves
  z += __shfl_xor(z, 32);
#pragma unroll
  for (int i = 0; i < 8; ++i) acc[i] += __shfl_xor(acc[i], 32);
  if (hlf == 0) {
    float inv = 1.f / z;
    half8v o;
#pragma unroll
    for (int i = 0; i < 8; ++i) o[i] = (_Float16)elu1(fmaf(acc[i], inv, bias[c * 8 + i]));
    *(half8v*)(outp + (long)wid * 256 + c * 8) = o;
  }
}

// ---------------------------------------------------------------------------
static inline int cdiv(int a, int b) { return (a + b - 1) / b; }

extern "C" void kernel_launch(void* const* d_in, const int* in_sizes, int n_in,
                              void* d_out, int out_size, void* d_ws, size_t ws_size,
                              hipStream_t stream) {
  const float* x = (const float*)d_in[0];
  const int* ei = (const int*)d_in[1];
  const float* W1 = (const float*)d_in[2];
  const float* as1 = (const float*)d_in[3];
  const float* ad1 = (const float*)d_in[4];
  const float* b1 = (const float*)d_in[5];
  const float* W2 = (const float*)d_in[6];
  const float* as2 = (const float*)d_in[7];
  const float* ad2 = (const float*)d_in[8];
  const float* b2 = (const float*)d_in[9];
  const float* lw1 = (const float*)d_in[10];
  const float* lb1 = (const float*)d_in[11];
  const float* lw2 = (const float*)d_in[12];
  const float* lb2 = (const float*)d_in[13];
  float* out = (float*)d_out;

  int N = in_sizes[0] / 128;  // 50000
  int E = in_sizes[1] / 2;    // 800000
  int Mp = cdiv(N, 64) * 64;  // 50048

  char* ws = (char*)d_ws;
  _Float16* Wt1 = (_Float16*)ws; ws += 256 * 128 * 2;
  _Float16* Wt2 = (_Float16*)ws; ws += 256 * 256 * 2;
  _Float16* WL = (_Float16*)ws; ws += 64 * 256 * 2;
  _Float16* C = (_Float16*)ws; ws += (size_t)Mp * 256 * 2;   // GEMM out
  _Float16* h2 = (_Float16*)ws; ws += (size_t)Mp * 256 * 2;  // aggregate out
  float* aS = (float*)ws; ws += (size_t)N * 4 * 4;
  float* aD = (float*)ws; ws += (size_t)N * 4 * 4;
  int* csr_src = (int*)ws; ws += (size_t)E * 4;
  int* indeg = (int*)ws; ws += (size_t)N * 4;
  int* cursor = (int*)ws; ws += (size_t)N * 4;
  int* off = (int*)ws; ws += (size_t)(N + 4) * 4;
  int* incl = (int*)ws; ws += (size_t)N * 4;
  int* bsum = (int*)ws; ws += 64 * 4;

  const int* e_src = ei;
  const int* e_dst = ei + E;
  int nb = cdiv(N, 1024);

  // weight conversion (one launch)
  convert_weights_kernel<<<cdiv(114688, 256), 256, 0, stream>>>(W1, W2, lw1, Wt1, Wt2, WL);

  // CSR build
  zero_int_kernel<<<cdiv(N, 256), 256, 0, stream>>>(indeg, N);
  count_kernel<<<cdiv(E, 256), 256, 0, stream>>>(e_dst, E, indeg);
  scan_block_kernel<<<nb, 1024, 0, stream>>>(indeg, incl, bsum, N);
  scan_finalize_kernel<<<cdiv(N, 256), 256, 0, stream>>>(indeg, incl, bsum, off, cursor, N);
  fill_kernel<<<cdiv(E, 256), 256, 0, stream>>>(e_src, e_dst, E, cursor, csr_src);

  // Layer 1 (A = fp32 x, converted in staging)
  mfma_gemm_attn_kernel<float><<<dim3(4, Mp / 64), 256, 0, stream>>>(x, Wt1, as1, ad1, C, aS, aD,
                                                                     N, 128);
  gat_aggregate5_kernel<<<cdiv(N, 4), 256, 0, stream>>>(C, aS, aD, off, csr_src, b1, h2, N);

  // Layer 2
  mfma_gemm_attn_kernel<_Float16><<<dim3(4, Mp / 64), 256, 0, stream>>>(h2, Wt2, as2, ad2, C, aS,
                                                                        aD, N, 256);
  gat_aggregate5_kernel<<<cdiv(N, 4), 256, 0, stream>>>(C, aS, aD, off, csr_src, b2, h2, N);

  // Head (MFMA, fused epilogue)
  head_mfma_kernel<<<Mp / 64, 256, 0, stream>>>(h2, WL, lb1, lw2, lb2, out, N);
}